// Round 13
// baseline (764.900 us; speedup 1.0000x reference)
//
#include <hip/hip_runtime.h>
#include <hip/hip_bf16.h>

// ---- problem constants ----
#define D_MODEL   512
#define D_STATE   128
#define D_CONV    4
#define HEADDIM   64
#define NLAYERS   2
#define D_INNER   1024
#define NHEADS    16
#define CONV_DIM  1280          // D_INNER + 2*D_STATE
#define D_IN_PROJ 2320          // 2*D_INNER + 2*D_STATE + NHEADS
#define NPAD      2432          // D_IN_PROJ padded to 128
#define SEQ       64
#define BATCH     512
#define NTOK      (BATCH*SEQ)   // 32768
#define FC_HID    128
#define EPS       1e-5f
#define YPITCH    1032          // D_INNER + 8 (LDS row pitch, 16B-aligned)

using bf16 = __hip_bfloat16;
typedef __bf16 bf16x8 __attribute__((ext_vector_type(8)));
typedef float  f32x4  __attribute__((ext_vector_type(4)));

__device__ __forceinline__ float b2f(bf16 v)  { return __bfloat162float(v); }
__device__ __forceinline__ bf16  f2b(float v) { return __float2bfloat16(v); }
__device__ __forceinline__ float bflo(unsigned u){ return __builtin_bit_cast(float, u << 16); }
__device__ __forceinline__ float bfhi(unsigned u){ return __builtin_bit_cast(float, u & 0xffff0000u); }

__device__ __forceinline__ void gl_lds16(const void* g, void* l) {
    __builtin_amdgcn_global_load_lds((const __attribute__((address_space(1))) void*)g,
                                     (__attribute__((address_space(3))) void*)l, 16, 0, 0);
}

// ---------------- embedding: h = emb[x]+pos (f32) and bf16 shadow hb ----------------
__global__ __launch_bounds__(256) void k_embed(const int* __restrict__ x,
        const float* __restrict__ emb, const float* __restrict__ pos,
        float* __restrict__ h, bf16* __restrict__ hb) {
    int idx = blockIdx.x*256 + threadIdx.x;     // NTOK*128
    int d   = (idx & 127) * 4;
    int tok = idx >> 7;
    int s   = tok & (SEQ-1);
    int v   = x[tok];
    float4 e4 = *(const float4*)(emb + (size_t)v*D_MODEL + d);
    float4 p4 = *(const float4*)(pos + (size_t)s*D_MODEL + d);
    float4 r; r.x=e4.x+p4.x; r.y=e4.y+p4.y; r.z=e4.z+p4.z; r.w=e4.w+p4.w;
    *(float4*)(h + (size_t)tok*D_MODEL + d) = r;
    bf16 o[4] = { f2b(r.x), f2b(r.y), f2b(r.z), f2b(r.w) };
    *(uint2*)(hb + (size_t)tok*D_MODEL + d) = *(uint2*)&o[0];
}

// ---------------- weight convert f32 -> bf16, zero-padded rows ----------------
__global__ __launch_bounds__(256) void k_cvtw(const float* __restrict__ src,
        bf16* __restrict__ dst, int R, int Kc, int total8) {
    int idx = blockIdx.x*256 + threadIdx.x;
    if (idx >= total8) return;
    int e0 = idx*8;
    int r = e0 / Kc, c = e0 % Kc;
    bf16 tb[8];
    if (r < R) {
        float4 f0 = *(const float4*)(src + (size_t)r*Kc + c);
        float4 f1 = *(const float4*)(src + (size_t)r*Kc + c + 4);
        tb[0]=f2b(f0.x); tb[1]=f2b(f0.y); tb[2]=f2b(f0.z); tb[3]=f2b(f0.w);
        tb[4]=f2b(f1.x); tb[5]=f2b(f1.y); tb[6]=f2b(f1.z); tb[7]=f2b(f1.w);
    } else {
        #pragma unroll
        for (int e=0;e<8;e++) tb[e] = f2b(0.f);
    }
    *(uint4*)(dst + (size_t)r*Kc + c) = *(uint4*)&tb[0];
}

// ---------------- GEMM 128x128 (round-7 best config: 64KB dbuf, issue-early, setprio) ----------------
// FUSE=1: in_proj epilogue (z / conv+silu / dt-scan). FUSE=0: plain store.
template<int FUSE, int KDIM>
__global__ __launch_bounds__(256) void k_gemm128(const bf16* __restrict__ A,
        const bf16* __restrict__ B, bf16* __restrict__ C,
        bf16* __restrict__ xbcc, float* __restrict__ dt, float* __restrict__ cum,
        const float* __restrict__ cw, const float* __restrict__ cb,
        const float* __restrict__ dt_bias, const float* __restrict__ A_log,
        int Nout, int nbx, int ctok)
{
    constexpr int NT = KDIM / 64;
    __shared__ __align__(16) char lds[65536];      // 2 buffers x (A 16K + B 16K)
    bf16* Cs = (bf16*)lds;                         // epilogue repack alias [128][136]

    // bijective XCD swizzle (m204)
    const int nwg = gridDim.x;
    const int q = nwg >> 3, r = nwg & 7;
    const int xcd = blockIdx.x & 7, loc = blockIdx.x >> 3;
    const int wg = ((xcd < r) ? xcd*(q+1) : r*(q+1) + (xcd-r)*q) + loc;
    const int m0 = (wg / nbx) * 128;
    const int n0 = (wg % nbx) * 128;

    const int t = threadIdx.x;
    const int wid = t >> 6, lane = t & 63;
    const int lr = lane & 15, lg = lane >> 4;
    const int wm = (wid >> 1)*64, wn = (wid & 1)*64;
    const int srow = wid*32;
    const int sr   = lane >> 3;                    // row-in-chunk 0..7
    const int scol = ((lane & 7) ^ sr) * 8;        // pre-swizzled source slot

    const bf16* Abase = A + (size_t)(m0 + srow + sr)*KDIM + scol;
    const bf16* Bbase = B + (size_t)(n0 + srow + sr)*KDIM + scol;

    f32x4 acc[4][4] = {};
    char* bc = lds;             // compute buffer
    char* bn = lds + 32768;     // staging buffer

    auto STAGE = [&](char* buf, int kk) {
        #pragma unroll
        for (int c = 0; c < 4; c++) {
            gl_lds16(Abase + (size_t)(c*8)*KDIM + kk, buf + (srow + c*8)*128);
            gl_lds16(Bbase + (size_t)(c*8)*KDIM + kk, buf + 16384 + (srow + c*8)*128);
        }
    };

    STAGE(bc, 0);
    asm volatile("s_waitcnt vmcnt(0)" ::: "memory");
    __builtin_amdgcn_s_barrier();

    #pragma unroll
    for (int kt = 0; kt < NT; kt++) {
        if (kt + 1 < NT) STAGE(bn, (kt+1)*64);     // issue-early: lands under MFMA
        #pragma unroll
        for (int ks = 0; ks < 64; ks += 32) {
            bf16x8 a[4], b[4];
            #pragma unroll
            for (int mi=0;mi<4;mi++) {
                int ra = wm + mi*16 + lr;
                a[mi] = *(const bf16x8*)(bc + ra*128 + ((((ks>>3)+lg) ^ (ra&7))<<4));
            }
            #pragma unroll
            for (int ni=0;ni<4;ni++) {
                int rb = wn + ni*16 + lr;
                b[ni] = *(const bf16x8*)(bc + 16384 + rb*128 + ((((ks>>3)+lg) ^ (rb&7))<<4));
            }
            __builtin_amdgcn_s_setprio(1);
            #pragma unroll
            for (int mi=0;mi<4;mi++)
                #pragma unroll
                for (int ni=0;ni<4;ni++)
                    acc[mi][ni] = __builtin_amdgcn_mfma_f32_16x16x32_bf16(a[mi], b[ni], acc[mi][ni], 0,0,0);
            __builtin_amdgcn_s_setprio(0);
        }
        asm volatile("s_waitcnt vmcnt(0)" ::: "memory");   // this iter's stage: hidden
        __builtin_amdgcn_s_barrier();
        char* tb2 = bc; bc = bn; bn = tb2;
    }
    __builtin_amdgcn_sched_barrier(0);

    // repack C tile into LDS (bank-safe: stride 136) — staging buffers dead
    #pragma unroll
    for (int mi=0;mi<4;mi++)
        #pragma unroll
        for (int ni=0;ni<4;ni++)
            #pragma unroll
            for (int rr=0;rr<4;rr++)
                Cs[(wm+mi*16+lg*4+rr)*136 + wn+ni*16+lr] = f2b(acc[mi][ni][rr]);
    __syncthreads();

    const int rsub = t >> 4;            // 0..15
    const int c8   = (t & 15) * 8;      // constant per thread across store loop

    if (FUSE == 0 || n0 < 1024) {
        const int strd = (FUSE == 0) ? Nout : 1024;
        #pragma unroll
        for (int it = 0; it < 8; it++) {
            int row = it*16 + rsub;
            *(uint4*)(C + (size_t)(m0+row)*strd + n0 + c8) = *(const uint4*)&Cs[row*136 + c8];
        }
    } else if (n0 < 2304) {
        // depthwise causal conv + silu -> xbcc
        const int cbase = n0 - 1024 + c8;
        float4 wreg[8]; float bias[8];
        #pragma unroll
        for (int e=0;e<8;e++) wreg[e] = *(const float4*)(cw + (size_t)(cbase+e)*4);
        {
            float4 b0 = *(const float4*)(cb + cbase);
            float4 b1 = *(const float4*)(cb + cbase + 4);
            bias[0]=b0.x; bias[1]=b0.y; bias[2]=b0.z; bias[3]=b0.w;
            bias[4]=b1.x; bias[5]=b1.y; bias[6]=b1.z; bias[7]=b1.w;
        }
        #pragma unroll
        for (int it = 0; it < 8; it++) {
            int row = it*16 + rsub;
            int sl  = row & (SEQ-1);
            float m3 = (sl >= 3) ? 1.f : 0.f;
            float m2 = (sl >= 2) ? 1.f : 0.f;
            float m1 = (sl >= 1) ? 1.f : 0.f;
            const bf16* sm3 = &Cs[(row-3)*136 + c8];
            const bf16* sm2 = &Cs[(row-2)*136 + c8];
            const bf16* sm1 = &Cs[(row-1)*136 + c8];
            const bf16* sm0 = &Cs[(row  )*136 + c8];
            float a[8];
            #pragma unroll
            for (int e=0;e<8;e++) {
                a[e] = bias[e]
                     + m3 * b2f(sm3[e]) * wreg[e].x
                     + m2 * b2f(sm2[e]) * wreg[e].y
                     + m1 * b2f(sm1[e]) * wreg[e].z
                     +      b2f(sm0[e]) * wreg[e].w;
            }
            bf16 outv[8];
            #pragma unroll
            for (int e=0;e<8;e++) outv[e] = f2b(a[e] / (1.f + __expf(-a[e])));
            *(uint4*)(xbcc + (size_t)(m0+row)*CONV_DIM + cbase) = *(uint4*)&outv[0];
        }
    } else {
        // dt tile: softplus + cumsum scan over each sequence, write dt/cum f32
        for (int p = wid; p < 32; p += 4) {       // (seq-in-tile, head)
            int sq = p >> 4, head = p & 15;
            float raw = b2f(Cs[(sq*64 + lane)*136 + head]) + dt_bias[head];
            float dval = (raw > 20.f) ? raw : log1pf(__expf(raw));
            float Ah = -__expf(A_log[head]);
            float cc = dval * Ah;
            #pragma unroll
            for (int o=1;o<64;o<<=1) { float v = __shfl_up(cc, o); if (lane >= o) cc += v; }
            int tok = m0 + sq*64 + lane;
            dt [(size_t)head*ctok + tok] = dval;
            cum[(size_t)head*ctok + tok] = cc;
        }
    }
}

// ---------------- SSD core v3: full batch per block + fused gate/RMS-norm ----------------
// One block per batch: 16 heads serially (scores in REGISTERS, no scores-LDS);
// per-head y written into block-wide LDS yb[64][YPITCH]. After all heads:
// gate with z, two-pass RMS (recompute silu -> bit-identical to v2 math), store once.
__global__ __launch_bounds__(256) void k_ssd(const bf16* __restrict__ xbcc,
        const float* __restrict__ dt, const float* __restrict__ cum,
        const float* __restrict__ Dskip, const bf16* __restrict__ zbuf,
        const float* __restrict__ nw, bf16* __restrict__ y, int ctok) {
    extern __shared__ __align__(16) char sm[];
    bf16* yb  = (bf16*)sm;                                   // [64][YPITCH] 132096 B
    bf16* Wb  = (bf16*)(sm + 64*YPITCH*2);                   // [64][72] 9216 B
    bf16* xsT = (bf16*)(sm + 64*YPITCH*2 + 9216);            // [64][72] 9216 B
    const int b = blockIdx.x;
    const int t = threadIdx.x;
    const size_t tokbase = (size_t)b*SEQ;
    const int lane = t & 63, lr = lane & 15, lg = lane >> 4;
    const int w = t >> 6;
    const int i0 = w*16;

    // scores kept in registers: sacc[jt][rr] = scores[i0+lg*4+rr][jt*16+lr]
    f32x4 sacc[4] = {};
    {
        const bf16* Cbase = xbcc + tokbase*CONV_DIM + D_INNER + D_STATE;
        const bf16* Bbase = xbcc + tokbase*CONV_DIM + D_INNER;
        #pragma unroll
        for (int ks = 0; ks < D_STATE; ks += 32) {
            bf16x8 af = *(const bf16x8*)(Cbase + (size_t)(i0+lr)*CONV_DIM + ks + lg*8);
            #pragma unroll
            for (int jt = 0; jt < 4; jt++) {
                bf16x8 bfr = *(const bf16x8*)(Bbase + (size_t)(jt*16+lr)*CONV_DIM + ks + lg*8);
                sacc[jt] = __builtin_amdgcn_mfma_f32_16x16x32_bf16(af, bfr, sacc[jt], 0,0,0);
            }
        }
    }

    for (int hh = 0; hh < NHEADS; hh++) {
        const size_t cbase = (size_t)hh*ctok + tokbase;
        __syncthreads();   // prev head's MFMA readers done -> Wb/xsT reusable

        // stage xsT (transpose xs)
        #pragma unroll
        for (int cc = 0; cc < 2; cc++) {
            int ch = cc*256 + t;
            int rr = ch >> 3, c8 = (ch & 7)*8;
            uint4 v = *(const uint4*)(xbcc + (tokbase + rr)*CONV_DIM + hh*HEADDIM + c8);
            const bf16* pv = (const bf16*)&v;
            #pragma unroll
            for (int e=0;e<8;e++) xsT[(c8+e)*72 + rr] = pv[e];
        }
        // build Wb straight from register scores
        {
            float cum_i[4], cum_j[4], dt_j[4];
            #pragma unroll
            for (int rr=0;rr<4;rr++) cum_i[rr] = cum[cbase + i0 + lg*4 + rr];
            #pragma unroll
            for (int jt=0;jt<4;jt++) { int j = jt*16+lr; cum_j[jt]=cum[cbase+j]; dt_j[jt]=dt[cbase+j]; }
            #pragma unroll
            for (int jt=0;jt<4;jt++)
                #pragma unroll
                for (int rr=0;rr<4;rr++) {
                    int i = i0 + lg*4 + rr, j = jt*16 + lr;
                    float wv = (j <= i) ? sacc[jt][rr] * __expf(cum_i[rr]-cum_j[jt]) * dt_j[jt] : 0.f;
                    Wb[i*72 + j] = f2b(wv);
                }
        }
        __syncthreads();

        // y = Wb @ xsT^T + Dskip*xs  -> yb[:, hh*64..]
        {
            float dsk = Dskip[hh];
            f32x4 yacc[4] = {};
            #pragma unroll
            for (int ks = 0; ks < 64; ks += 32) {
                bf16x8 a = *(const bf16x8*)&Wb[(w*16 + lr)*72 + ks + lg*8];
                #pragma unroll
                for (int n=0; n<4; n++) {
                    bf16x8 bb = *(const bf16x8*)&xsT[(n*16 + lr)*72 + ks + lg*8];
                    yacc[n] = __builtin_amdgcn_mfma_f32_16x16x32_bf16(a, bb, yacc[n], 0,0,0);
                }
            }
            #pragma unroll
            for (int n=0; n<4; n++)
                #pragma unroll
                for (int rr=0; rr<4; rr++) {
                    int row = w*16 + lg*4 + rr;
                    int col = n*16 + lr;
                    yb[row*YPITCH + hh*HEADDIM + col] = f2b(yacc[n][rr] + dsk * b2f(xsT[col*72 + row]));
                }
        }
    }
    __syncthreads();   // yb complete

    // ---- fused gate + RMS-norm (two-pass: identical math to separate kernel) ----
    {
        const int tok = t >> 2, cg = (t & 3) * 256;
        const bf16* zrow = zbuf + (tokbase + tok)*D_INNER + cg;
        const bf16* ybrow = yb + tok*YPITCH + cg;
        float ss = 0.f;
        #pragma unroll
        for (int i2 = 0; i2 < 32; i2++) {
            uint4 yv = *(const uint4*)(ybrow + i2*8);
            uint4 zv = *(const uint4*)(zrow  + i2*8);
            const unsigned* yu = (const unsigned*)&yv;
            const unsigned* zu = (const unsigned*)&zv;
            #pragma unroll
            for (int e=0;e<4;e++) {
                float y0 = bflo(yu[e]), y1 = bfhi(yu[e]);
                float z0 = bflo(zu[e]), z1 = bfhi(zu[e]);
                float g0 = y0 * z0 / (1.f + __expf(-z0));
                float g1 = y1 * z1 / (1.f + __expf(-z1));
                ss += g0*g0 + g1*g1;
            }
        }
        ss += __shfl_xor(ss, 1);
        ss += __shfl_xor(ss, 2);
        float scale = rsqrtf(ss/(float)D_INNER + EPS);
        bf16* dst = y + (tokbase + tok)*D_INNER + cg;
        #pragma unroll
        for (int i2 = 0; i2 < 32; i2++) {
            uint4 yv = *(const uint4*)(ybrow + i2*8);
            uint4 zv = *(const uint4*)(zrow  + i2*8);
            const unsigned* yu = (const unsigned*)&yv;
            const unsigned* zu = (const unsigned*)&zv;
            float4 n0 = *(const float4*)(nw + cg + i2*8);
            float4 n1 = *(const float4*)(nw + cg + i2*8 + 4);
            const float* nn = (const float*)&n0;
            const float* nn2 = (const float*)&n1;
            bf16 outv[8];
            #pragma unroll
            for (int e=0;e<4;e++) {
                float y0 = bflo(yu[e]), y1 = bfhi(yu[e]);
                float z0 = bflo(zu[e]), z1 = bfhi(zu[e]);
                float g0 = y0 * z0 / (1.f + __expf(-z0));
                float g1 = y1 * z1 / (1.f + __expf(-z1));
                float w0 = (2*e   < 4) ? nn[2*e]   : nn2[2*e-4];
                float w1 = (2*e+1 < 4) ? nn[2*e+1] : nn2[2*e+1-4];
                outv[2*e]   = f2b(g0 * scale * w0);
                outv[2*e+1] = f2b(g1 * scale * w1);
            }
            *(uint4*)(dst + i2*8) = *(uint4*)&outv[0];
        }
    }
}

// ---------------- h += layernorm(tmp)*g + b; refresh hb (2 tokens/block) ----------------
__global__ __launch_bounds__(256) void k_resln(float* __restrict__ h,
        bf16* __restrict__ hb, const bf16* __restrict__ tmp,
        const float* __restrict__ g, const float* __restrict__ bb) {
    int tok = blockIdx.x*2 + (threadIdx.x >> 7);
    int t   = threadIdx.x & 127;
    int hi  = threadIdx.x >> 7, wv = (threadIdx.x >> 6) & 1;
    __shared__ float redS[2][2], redQ[2][2];
    int d = t*4;
    uint2 u2 = *(const uint2*)(tmp + (size_t)tok*D_MODEL + d);
    const unsigned* uu = (const unsigned*)&u2;
    float v0 = bflo(uu[0]), v1 = bfhi(uu[0]), v2 = bflo(uu[1]), v3 = bfhi(uu[1]);
    float s = v0+v1+v2+v3;
    float qq = v0*v0+v1*v1+v2*v2+v3*v3;
    for (int o=32;o>0;o>>=1){ s += __shfl_down(s,o); qq += __shfl_down(qq,o); }
    if ((threadIdx.x & 63) == 0){ redS[hi][wv]=s; redQ[hi][wv]=qq; }
    __syncthreads();
    float S = redS[hi][0]+redS[hi][1];
    float Q = redQ[hi][0]+redQ[hi][1];
    float mu  = S/(float)D_MODEL;
    float var = Q/(float)D_MODEL - mu*mu;
    float inv = rsqrtf(var + EPS);
    size_t base = (size_t)tok*D_MODEL + d;
    float4 h4 = *(const float4*)(h + base);
    float4 g4 = *(const float4*)(g + d);
    float4 b4 = *(const float4*)(bb + d);
    h4.x += (v0-mu)*inv*g4.x + b4.x;
    h4.y += (v1-mu)*inv*g4.y + b4.y;
    h4.z += (v2-mu)*inv*g4.z + b4.z;
    h4.w += (v3-mu)*inv*g4.w + b4.w;
    *(float4*)(h + base) = h4;
    bf16 o4[4] = { f2b(h4.x), f2b(h4.y), f2b(h4.z), f2b(h4.w) };
    *(uint2*)(hb + base) = *(uint2*)&o4[0];
}

// ---------------- masked mean-pool over s ----------------
__global__ __launch_bounds__(256) void k_pool(const float* __restrict__ h,
        float* __restrict__ pooled) {
    int b = blockIdx.x, t = threadIdx.x;
    __shared__ float ps[64][4];
    __shared__ float pm[64];
    __shared__ float cntS;
    {
        int s = t >> 2, qq = t & 3;
        const float4* row = (const float4*)(h + ((size_t)b*SEQ + s)*D_MODEL + qq*128);
        float acc = 0;
        #pragma unroll 8
        for (int e=0;e<32;e++) { float4 f = row[e]; acc += f.x+f.y+f.z+f.w; }
        ps[s][qq] = acc;
    }
    __syncthreads();
    if (t < 64) pm[t] = (ps[t][0]+ps[t][1]+ps[t][2]+ps[t][3]) != 0.f ? 1.f : 0.f;
    __syncthreads();
    if (t == 0) { float c=0; for (int s2=0;s2<64;s2++) c+=pm[s2]; cntS = fmaxf(c,1.f); }
    __syncthreads();
    float cnt = cntS;
    #pragma unroll
    for (int rep=0;rep<2;rep++) {
        int d = t + rep*256;
        float acc = 0;
        for (int s2=0;s2<64;s2++) acc += h[((size_t)b*SEQ+s2)*D_MODEL + d] * pm[s2];
        pooled[(size_t)b*D_MODEL + d] = acc / cnt;
    }
}

// ---------------- fc1(relu) + fc2 ----------------
__global__ __launch_bounds__(128) void k_fc(const float* __restrict__ pooled,
        const float* __restrict__ w1, const float* __restrict__ b1,
        const float* __restrict__ w2, const float* __restrict__ b2,
        float* __restrict__ out) {
    int b = blockIdx.x, j = threadIdx.x;
    __shared__ float hid[FC_HID];
    const float* p  = pooled + (size_t)b*D_MODEL;
    const float* wr = w1 + (size_t)j*D_MODEL;
    float acc = b1[j];
    for (int d=0; d<D_MODEL; d+=4)
        acc += p[d]*wr[d] + p[d+1]*wr[d+1] + p[d+2]*wr[d+2] + p[d+3]*wr[d+3];
    hid[j] = fmaxf(acc, 0.f);
    __syncthreads();
    if (j < 2) {
        float o = b2[j];
        for (int k=0;k<FC_HID;k++) o += hid[k]*w2[j*FC_HID+k];
        out[b*2 + j] = o;
    }
}

extern "C" void kernel_launch(void* const* d_in, const int* in_sizes, int n_in,
                              void* d_out, int out_size, void* d_ws, size_t ws_size,
                              hipStream_t stream) {
    (void)in_sizes; (void)n_in; (void)out_size;
    const int*   x        = (const int*)  d_in[0];
    const float* emb      = (const float*)d_in[1];
    const float* pos      = (const float*)d_in[2];
    const float* in_proj  = (const float*)d_in[3];
    const float* conv_w   = (const float*)d_in[4];
    const float* conv_b   = (const float*)d_in[5];
    const float* dt_bias  = (const float*)d_in[6];
    const float* A_log    = (const float*)d_in[7];
    const float* D_skip   = (const float*)d_in[8];
    const float* norm_w   = (const float*)d_in[9];
    const float* out_proj = (const float*)d_in[10];
    const float* ln_g     = (const float*)d_in[11];
    const float* ln_b     = (const float*)d_in[12];
    const float* fc1_w    = (const float*)d_in[13];
    const float* fc1_b    = (const float*)d_in[14];
    const float* fc2_w    = (const float*)d_in[15];
    const float* fc2_b    = (const float*)d_in[16];
    float* out = (float*)d_out;

    // allow 150528 B dynamic LDS for fused SSD (idempotent, deterministic)
    const int SSD_LDS = 64*YPITCH*2 + 2*9216;     // 150528
    (void)hipFuncSetAttribute((const void*)k_ssd,
            hipFuncAttributeMaxDynamicSharedMemorySize, SSD_LDS);

    // ---- persistent region ----
    const size_t H_B   = (size_t)NTOK * D_MODEL * 4;     // 64 MB f32 h
    const size_t HB_B  = (size_t)NTOK * D_MODEL * 2;     // 32 MB bf16 shadow
    const size_t WPI_B = (size_t)NPAD * D_MODEL * 2;     // per layer 2.49 MB
    const size_t WPO_B = (size_t)D_MODEL * D_INNER * 2;  // per layer 1 MB
    const size_t PBASE = H_B + HB_B + NLAYERS*(WPI_B + WPO_B);

    // transients per token: z 2048 + xbcc 2560 + ybuf 2048 + dt/cum 128
    const size_t PER_TOK = 2048 + 2560 + 2048 + 128;     // 6784 B
    int CB = BATCH;
    while (CB > 8 && PBASE + (size_t)CB*SEQ*PER_TOK > ws_size) CB >>= 1;
    const int CT = CB * SEQ;
    const int NC = BATCH / CB;

    char* ws = (char*)d_ws;
    float* h    = (float*)(ws);
    bf16*  hb   = (bf16*) (ws + H_B);
    bf16*  wpi  = (bf16*) (ws + H_B + HB_B);                   // [NLAYERS][NPAD][512]
    bf16*  wpo  = (bf16*) (ws + H_B + HB_B + NLAYERS*WPI_B);   // [NLAYERS][512][1024]
    char*  tr   = ws + PBASE;
    bf16*  zbuf = (bf16*) (tr);                                // CT*1024
    bf16*  xbcc = (bf16*) (tr + (size_t)CT*2048);              // CT*1280
    bf16*  ybuf = (bf16*) (tr + (size_t)CT*(2048+2560));       // CT*1024
    float* dt   = (float*)(tr + (size_t)CT*(2048+2560+2048));  // [16][CT]
    float* cum  = dt + (size_t)CT*NHEADS;
    bf16*  tmp  = xbcc;                 // alias: xbcc dead after k_ssd
    float* pooled = (float*)tr;

    // weight conversion (both layers, once per launch)
    for (int l = 0; l < NLAYERS; l++) {
        int t8i = NPAD*D_MODEL/8;
        k_cvtw<<<(t8i+255)/256, 256, 0, stream>>>(in_proj + (size_t)l*D_IN_PROJ*D_MODEL,
                wpi + (size_t)l*NPAD*D_MODEL, D_IN_PROJ, D_MODEL, t8i);
        int t8o = D_MODEL*D_INNER/8;
        k_cvtw<<<(t8o+255)/256, 256, 0, stream>>>(out_proj + (size_t)l*D_MODEL*D_INNER,
                wpo + (size_t)l*D_MODEL*D_INNER, D_MODEL, D_INNER, t8o);
    }

    k_embed<<<(NTOK*128)/256, 256, 0, stream>>>(x, emb, pos, h, hb);

    const int NBX_I = NPAD/128;     // 19
    const int NBX_O = D_MODEL/128;  // 4

    for (int l = 0; l < NLAYERS; l++) {
        const bf16* wi = wpi + (size_t)l*NPAD*D_MODEL;
        const bf16* wo = wpo + (size_t)l*D_MODEL*D_INNER;
        for (int c = 0; c < NC; c++) {
            const int tok0 = c * CT;
            float* hc  = h  + (size_t)tok0 * D_MODEL;
            bf16*  hbc = hb + (size_t)tok0 * D_MODEL;
            k_gemm128<1,512><<<(CT/128)*NBX_I, 256, 0, stream>>>(hbc, wi, zbuf,
                    xbcc, dt, cum,
                    conv_w + (size_t)l*CONV_DIM*D_CONV, conv_b + (size_t)l*CONV_DIM,
                    dt_bias + l*NHEADS, A_log + l*NHEADS,
                    NPAD, NBX_I, CT);
            k_ssd<<<CB, 256, SSD_LDS, stream>>>(xbcc, dt, cum, D_skip + l*NHEADS,
                    zbuf, norm_w + (size_t)l*D_INNER, ybuf, CT);
            k_gemm128<0,1024><<<(CT/128)*NBX_O, 256, 0, stream>>>(ybuf, wo, tmp,
                    nullptr, nullptr, nullptr, nullptr, nullptr, nullptr, nullptr,
                    D_MODEL, NBX_O, CT);
            k_resln<<<CT/2, 256, 0, stream>>>(hc, hbc, tmp, ln_g + l*D_MODEL, ln_b + l*D_MODEL);
        }
    }

    k_pool<<<BATCH, 256, 0, stream>>>(h, pooled);
    k_fc<<<BATCH, FC_HID, 0, stream>>>(pooled, fc1_w, fc1_b, fc2_w, fc2_b, out);
}

// Round 14
// 666.739 us; speedup vs baseline: 1.1472x; 1.1472x over previous
//
#include <hip/hip_runtime.h>
#include <hip/hip_bf16.h>

// ---- problem constants ----
#define D_MODEL   512
#define D_STATE   128
#define D_CONV    4
#define HEADDIM   64
#define NLAYERS   2
#define D_INNER   1024
#define NHEADS    16
#define CONV_DIM  1280          // D_INNER + 2*D_STATE
#define D_IN_PROJ 2320          // 2*D_INNER + 2*D_STATE + NHEADS
#define NPAD      2432          // D_IN_PROJ padded to 128
#define SEQ       64
#define BATCH     512
#define NTOK      (BATCH*SEQ)   // 32768
#define FC_HID    128
#define EPS       1e-5f
#define YPITCH    1032          // D_INNER + 8 (LDS row pitch, 16B-aligned)

using bf16 = __hip_bfloat16;
typedef __bf16 bf16x8 __attribute__((ext_vector_type(8)));
typedef float  f32x4  __attribute__((ext_vector_type(4)));

__device__ __forceinline__ float b2f(bf16 v)  { return __bfloat162float(v); }
__device__ __forceinline__ bf16  f2b(float v) { return __float2bfloat16(v); }
__device__ __forceinline__ float bflo(unsigned u){ return __builtin_bit_cast(float, u << 16); }
__device__ __forceinline__ float bfhi(unsigned u){ return __builtin_bit_cast(float, u & 0xffff0000u); }

__device__ __forceinline__ void gl_lds16(const void* g, void* l) {
    __builtin_amdgcn_global_load_lds((const __attribute__((address_space(1))) void*)g,
                                     (__attribute__((address_space(3))) void*)l, 16, 0, 0);
}

// ---------------- embedding: h = emb[x]+pos (f32) and bf16 shadow hb ----------------
__global__ __launch_bounds__(256) void k_embed(const int* __restrict__ x,
        const float* __restrict__ emb, const float* __restrict__ pos,
        float* __restrict__ h, bf16* __restrict__ hb) {
    int idx = blockIdx.x*256 + threadIdx.x;     // NTOK*128
    int d   = (idx & 127) * 4;
    int tok = idx >> 7;
    int s   = tok & (SEQ-1);
    int v   = x[tok];
    float4 e4 = *(const float4*)(emb + (size_t)v*D_MODEL + d);
    float4 p4 = *(const float4*)(pos + (size_t)s*D_MODEL + d);
    float4 r; r.x=e4.x+p4.x; r.y=e4.y+p4.y; r.z=e4.z+p4.z; r.w=e4.w+p4.w;
    *(float4*)(h + (size_t)tok*D_MODEL + d) = r;
    bf16 o[4] = { f2b(r.x), f2b(r.y), f2b(r.z), f2b(r.w) };
    *(uint2*)(hb + (size_t)tok*D_MODEL + d) = *(uint2*)&o[0];
}

// ---------------- weight convert f32 -> bf16, zero-padded rows ----------------
__global__ __launch_bounds__(256) void k_cvtw(const float* __restrict__ src,
        bf16* __restrict__ dst, int R, int Kc, int total8) {
    int idx = blockIdx.x*256 + threadIdx.x;
    if (idx >= total8) return;
    int e0 = idx*8;
    int r = e0 / Kc, c = e0 % Kc;
    bf16 tb[8];
    if (r < R) {
        float4 f0 = *(const float4*)(src + (size_t)r*Kc + c);
        float4 f1 = *(const float4*)(src + (size_t)r*Kc + c + 4);
        tb[0]=f2b(f0.x); tb[1]=f2b(f0.y); tb[2]=f2b(f0.z); tb[3]=f2b(f0.w);
        tb[4]=f2b(f1.x); tb[5]=f2b(f1.y); tb[6]=f2b(f1.z); tb[7]=f2b(f1.w);
    } else {
        #pragma unroll
        for (int e=0;e<8;e++) tb[e] = f2b(0.f);
    }
    *(uint4*)(dst + (size_t)r*Kc + c) = *(uint4*)&tb[0];
}

// ---------------- GEMM 128x128 (round-7 best config: 64KB dbuf, issue-early, setprio) ----------------
// FUSE=1: in_proj epilogue (z / conv+silu / dt-scan). FUSE=0: plain store.
template<int FUSE, int KDIM>
__global__ __launch_bounds__(256) void k_gemm128(const bf16* __restrict__ A,
        const bf16* __restrict__ B, bf16* __restrict__ C,
        bf16* __restrict__ xbcc, float* __restrict__ dt, float* __restrict__ cum,
        const float* __restrict__ cw, const float* __restrict__ cb,
        const float* __restrict__ dt_bias, const float* __restrict__ A_log,
        int Nout, int nbx, int ctok)
{
    constexpr int NT = KDIM / 64;
    __shared__ __align__(16) char lds[65536];      // 2 buffers x (A 16K + B 16K)
    bf16* Cs = (bf16*)lds;                         // epilogue repack alias [128][136]

    // bijective XCD swizzle (m204)
    const int nwg = gridDim.x;
    const int q = nwg >> 3, r = nwg & 7;
    const int xcd = blockIdx.x & 7, loc = blockIdx.x >> 3;
    const int wg = ((xcd < r) ? xcd*(q+1) : r*(q+1) + (xcd-r)*q) + loc;
    const int m0 = (wg / nbx) * 128;
    const int n0 = (wg % nbx) * 128;

    const int t = threadIdx.x;
    const int wid = t >> 6, lane = t & 63;
    const int lr = lane & 15, lg = lane >> 4;
    const int wm = (wid >> 1)*64, wn = (wid & 1)*64;
    const int srow = wid*32;
    const int sr   = lane >> 3;                    // row-in-chunk 0..7
    const int scol = ((lane & 7) ^ sr) * 8;        // pre-swizzled source slot

    const bf16* Abase = A + (size_t)(m0 + srow + sr)*KDIM + scol;
    const bf16* Bbase = B + (size_t)(n0 + srow + sr)*KDIM + scol;

    f32x4 acc[4][4] = {};
    char* bc = lds;             // compute buffer
    char* bn = lds + 32768;     // staging buffer

    auto STAGE = [&](char* buf, int kk) {
        #pragma unroll
        for (int c = 0; c < 4; c++) {
            gl_lds16(Abase + (size_t)(c*8)*KDIM + kk, buf + (srow + c*8)*128);
            gl_lds16(Bbase + (size_t)(c*8)*KDIM + kk, buf + 16384 + (srow + c*8)*128);
        }
    };

    STAGE(bc, 0);
    asm volatile("s_waitcnt vmcnt(0)" ::: "memory");
    __builtin_amdgcn_s_barrier();

    #pragma unroll
    for (int kt = 0; kt < NT; kt++) {
        if (kt + 1 < NT) STAGE(bn, (kt+1)*64);     // issue-early: lands under MFMA
        #pragma unroll
        for (int ks = 0; ks < 64; ks += 32) {
            bf16x8 a[4], b[4];
            #pragma unroll
            for (int mi=0;mi<4;mi++) {
                int ra = wm + mi*16 + lr;
                a[mi] = *(const bf16x8*)(bc + ra*128 + ((((ks>>3)+lg) ^ (ra&7))<<4));
            }
            #pragma unroll
            for (int ni=0;ni<4;ni++) {
                int rb = wn + ni*16 + lr;
                b[ni] = *(const bf16x8*)(bc + 16384 + rb*128 + ((((ks>>3)+lg) ^ (rb&7))<<4));
            }
            __builtin_amdgcn_s_setprio(1);
            #pragma unroll
            for (int mi=0;mi<4;mi++)
                #pragma unroll
                for (int ni=0;ni<4;ni++)
                    acc[mi][ni] = __builtin_amdgcn_mfma_f32_16x16x32_bf16(a[mi], b[ni], acc[mi][ni], 0,0,0);
            __builtin_amdgcn_s_setprio(0);
        }
        asm volatile("s_waitcnt vmcnt(0)" ::: "memory");   // this iter's stage: hidden
        __builtin_amdgcn_s_barrier();
        char* tb2 = bc; bc = bn; bn = tb2;
    }
    __builtin_amdgcn_sched_barrier(0);

    // repack C tile into LDS (bank-safe: stride 136) — staging buffers dead
    #pragma unroll
    for (int mi=0;mi<4;mi++)
        #pragma unroll
        for (int ni=0;ni<4;ni++)
            #pragma unroll
            for (int rr=0;rr<4;rr++)
                Cs[(wm+mi*16+lg*4+rr)*136 + wn+ni*16+lr] = f2b(acc[mi][ni][rr]);
    __syncthreads();

    const int rsub = t >> 4;            // 0..15
    const int c8   = (t & 15) * 8;      // constant per thread across store loop

    if (FUSE == 0 || n0 < 1024) {
        const int strd = (FUSE == 0) ? Nout : 1024;
        #pragma unroll
        for (int it = 0; it < 8; it++) {
            int row = it*16 + rsub;
            *(uint4*)(C + (size_t)(m0+row)*strd + n0 + c8) = *(const uint4*)&Cs[row*136 + c8];
        }
    } else if (n0 < 2304) {
        // depthwise causal conv + silu -> xbcc
        const int cbase = n0 - 1024 + c8;
        float4 wreg[8]; float bias[8];
        #pragma unroll
        for (int e=0;e<8;e++) wreg[e] = *(const float4*)(cw + (size_t)(cbase+e)*4);
        {
            float4 b0 = *(const float4*)(cb + cbase);
            float4 b1 = *(const float4*)(cb + cbase + 4);
            bias[0]=b0.x; bias[1]=b0.y; bias[2]=b0.z; bias[3]=b0.w;
            bias[4]=b1.x; bias[5]=b1.y; bias[6]=b1.z; bias[7]=b1.w;
        }
        #pragma unroll
        for (int it = 0; it < 8; it++) {
            int row = it*16 + rsub;
            int sl  = row & (SEQ-1);
            float m3 = (sl >= 3) ? 1.f : 0.f;
            float m2 = (sl >= 2) ? 1.f : 0.f;
            float m1 = (sl >= 1) ? 1.f : 0.f;
            const bf16* sm3 = &Cs[(row-3)*136 + c8];
            const bf16* sm2 = &Cs[(row-2)*136 + c8];
            const bf16* sm1 = &Cs[(row-1)*136 + c8];
            const bf16* sm0 = &Cs[(row  )*136 + c8];
            float a[8];
            #pragma unroll
            for (int e=0;e<8;e++) {
                a[e] = bias[e]
                     + m3 * b2f(sm3[e]) * wreg[e].x
                     + m2 * b2f(sm2[e]) * wreg[e].y
                     + m1 * b2f(sm1[e]) * wreg[e].z
                     +      b2f(sm0[e]) * wreg[e].w;
            }
            bf16 outv[8];
            #pragma unroll
            for (int e=0;e<8;e++) outv[e] = f2b(a[e] / (1.f + __expf(-a[e])));
            *(uint4*)(xbcc + (size_t)(m0+row)*CONV_DIM + cbase) = *(uint4*)&outv[0];
        }
    } else {
        // dt tile: softplus + cumsum scan over each sequence, write dt/cum f32
        for (int p = wid; p < 32; p += 4) {       // (seq-in-tile, head)
            int sq = p >> 4, head = p & 15;
            float raw = b2f(Cs[(sq*64 + lane)*136 + head]) + dt_bias[head];
            float dval = (raw > 20.f) ? raw : log1pf(__expf(raw));
            float Ah = -__expf(A_log[head]);
            float cc = dval * Ah;
            #pragma unroll
            for (int o=1;o<64;o<<=1) { float v = __shfl_up(cc, o); if (lane >= o) cc += v; }
            int tok = m0 + sq*64 + lane;
            dt [(size_t)head*ctok + tok] = dval;
            cum[(size_t)head*ctok + tok] = cc;
        }
    }
}

// ---------------- SSD core v3b: full batch per block + fused gate/RMS (wave-per-token) ----------------
// One block per batch: 16 heads serially (scores in REGISTERS); per-head y -> LDS yb.
// Gate/RMS phase: wave w handles token pass*4+w, lane l covers elements l*16..+15
// (wave = 2 KB contiguous -> coalesced; round-13 had 512B-stride scatter = 4x write amp).
__global__ __launch_bounds__(256) void k_ssd(const bf16* __restrict__ xbcc,
        const float* __restrict__ dt, const float* __restrict__ cum,
        const float* __restrict__ Dskip, const bf16* __restrict__ zbuf,
        const float* __restrict__ nw, bf16* __restrict__ y, int ctok) {
    extern __shared__ __align__(16) char sm[];
    bf16* yb  = (bf16*)sm;                                   // [64][YPITCH] 132096 B
    bf16* Wb  = (bf16*)(sm + 64*YPITCH*2);                   // [64][72] 9216 B
    bf16* xsT = (bf16*)(sm + 64*YPITCH*2 + 9216);            // [64][72] 9216 B
    const int b = blockIdx.x;
    const int t = threadIdx.x;
    const size_t tokbase = (size_t)b*SEQ;
    const int lane = t & 63, lr = lane & 15, lg = lane >> 4;
    const int w = t >> 6;
    const int i0 = w*16;

    // scores kept in registers: sacc[jt][rr] = scores[i0+lg*4+rr][jt*16+lr]
    f32x4 sacc[4] = {};
    {
        const bf16* Cbase = xbcc + tokbase*CONV_DIM + D_INNER + D_STATE;
        const bf16* Bbase = xbcc + tokbase*CONV_DIM + D_INNER;
        #pragma unroll
        for (int ks = 0; ks < D_STATE; ks += 32) {
            bf16x8 af = *(const bf16x8*)(Cbase + (size_t)(i0+lr)*CONV_DIM + ks + lg*8);
            #pragma unroll
            for (int jt = 0; jt < 4; jt++) {
                bf16x8 bfr = *(const bf16x8*)(Bbase + (size_t)(jt*16+lr)*CONV_DIM + ks + lg*8);
                sacc[jt] = __builtin_amdgcn_mfma_f32_16x16x32_bf16(af, bfr, sacc[jt], 0,0,0);
            }
        }
    }

    for (int hh = 0; hh < NHEADS; hh++) {
        const size_t cbase = (size_t)hh*ctok + tokbase;
        __syncthreads();   // prev head's MFMA readers done -> Wb/xsT reusable

        // stage xsT (transpose xs)
        #pragma unroll
        for (int cc = 0; cc < 2; cc++) {
            int ch = cc*256 + t;
            int rr = ch >> 3, c8 = (ch & 7)*8;
            uint4 v = *(const uint4*)(xbcc + (tokbase + rr)*CONV_DIM + hh*HEADDIM + c8);
            const bf16* pv = (const bf16*)&v;
            #pragma unroll
            for (int e=0;e<8;e++) xsT[(c8+e)*72 + rr] = pv[e];
        }
        // build Wb straight from register scores
        {
            float cum_i[4], cum_j[4], dt_j[4];
            #pragma unroll
            for (int rr=0;rr<4;rr++) cum_i[rr] = cum[cbase + i0 + lg*4 + rr];
            #pragma unroll
            for (int jt=0;jt<4;jt++) { int j = jt*16+lr; cum_j[jt]=cum[cbase+j]; dt_j[jt]=dt[cbase+j]; }
            #pragma unroll
            for (int jt=0;jt<4;jt++)
                #pragma unroll
                for (int rr=0;rr<4;rr++) {
                    int i = i0 + lg*4 + rr, j = jt*16 + lr;
                    float wv = (j <= i) ? sacc[jt][rr] * __expf(cum_i[rr]-cum_j[jt]) * dt_j[jt] : 0.f;
                    Wb[i*72 + j] = f2b(wv);
                }
        }
        __syncthreads();

        // y = Wb @ xsT^T + Dskip*xs  -> yb[:, hh*64..]
        {
            float dsk = Dskip[hh];
            f32x4 yacc[4] = {};
            #pragma unroll
            for (int ks = 0; ks < 64; ks += 32) {
                bf16x8 a = *(const bf16x8*)&Wb[(w*16 + lr)*72 + ks + lg*8];
                #pragma unroll
                for (int n=0; n<4; n++) {
                    bf16x8 bb = *(const bf16x8*)&xsT[(n*16 + lr)*72 + ks + lg*8];
                    yacc[n] = __builtin_amdgcn_mfma_f32_16x16x32_bf16(a, bb, yacc[n], 0,0,0);
                }
            }
            #pragma unroll
            for (int n=0; n<4; n++)
                #pragma unroll
                for (int rr=0; rr<4; rr++) {
                    int row = w*16 + lg*4 + rr;
                    int col = n*16 + lr;
                    yb[row*YPITCH + hh*HEADDIM + col] = f2b(yacc[n][rr] + dsk * b2f(xsT[col*72 + row]));
                }
        }
    }
    __syncthreads();   // yb complete

    // ---- fused gate + RMS-norm, wave-per-token (coalesced) ----
    for (int pass = 0; pass < 16; pass++) {
        const int tok = pass*4 + w;
        const int d0  = lane*16;                   // 16 elements per lane
        const bf16* zrow  = zbuf + (tokbase + tok)*D_INNER + d0;
        const bf16* ybrow = yb + tok*YPITCH + d0;
        uint4 yv0 = *(const uint4*)(ybrow);
        uint4 yv1 = *(const uint4*)(ybrow + 8);
        uint4 zv0 = *(const uint4*)(zrow);
        uint4 zv1 = *(const uint4*)(zrow + 8);
        const unsigned* yu0 = (const unsigned*)&yv0;
        const unsigned* yu1 = (const unsigned*)&yv1;
        const unsigned* zu0 = (const unsigned*)&zv0;
        const unsigned* zu1 = (const unsigned*)&zv1;
        float g[16]; float ss = 0.f;
        #pragma unroll
        for (int e=0;e<4;e++) {
            float y0 = bflo(yu0[e]), y1 = bfhi(yu0[e]);
            float z0 = bflo(zu0[e]), z1 = bfhi(zu0[e]);
            float g0 = y0 * z0 / (1.f + __expf(-z0));
            float g1 = y1 * z1 / (1.f + __expf(-z1));
            g[2*e] = g0; g[2*e+1] = g1;
            ss += g0*g0 + g1*g1;
            float y2 = bflo(yu1[e]), y3 = bfhi(yu1[e]);
            float z2 = bflo(zu1[e]), z3 = bfhi(zu1[e]);
            float g2 = y2 * z2 / (1.f + __expf(-z2));
            float g3 = y3 * z3 / (1.f + __expf(-z3));
            g[8+2*e] = g2; g[8+2*e+1] = g3;
            ss += g2*g2 + g3*g3;
        }
        #pragma unroll
        for (int o=32;o>0;o>>=1) ss += __shfl_xor(ss, o);
        float scale = rsqrtf(ss/(float)D_INNER + EPS);
        bf16 outv[16];
        #pragma unroll
        for (int e=0;e<16;e++) outv[e] = f2b(g[e] * scale * nw[d0+e]);
        bf16* dst = y + (tokbase + tok)*D_INNER + d0;
        *(uint4*)dst     = *(uint4*)&outv[0];
        *(uint4*)(dst+8) = *(uint4*)&outv[8];
    }
}

// ---------------- h += layernorm(tmp)*g + b; refresh hb (2 tokens/block) ----------------
__global__ __launch_bounds__(256) void k_resln(float* __restrict__ h,
        bf16* __restrict__ hb, const bf16* __restrict__ tmp,
        const float* __restrict__ g, const float* __restrict__ bb) {
    int tok = blockIdx.x*2 + (threadIdx.x >> 7);
    int t   = threadIdx.x & 127;
    int hi  = threadIdx.x >> 7, wv = (threadIdx.x >> 6) & 1;
    __shared__ float redS[2][2], redQ[2][2];
    int d = t*4;
    uint2 u2 = *(const uint2*)(tmp + (size_t)tok*D_MODEL + d);
    const unsigned* uu = (const unsigned*)&u2;
    float v0 = bflo(uu[0]), v1 = bfhi(uu[0]), v2 = bflo(uu[1]), v3 = bfhi(uu[1]);
    float s = v0+v1+v2+v3;
    float qq = v0*v0+v1*v1+v2*v2+v3*v3;
    for (int o=32;o>0;o>>=1){ s += __shfl_down(s,o); qq += __shfl_down(qq,o); }
    if ((threadIdx.x & 63) == 0){ redS[hi][wv]=s; redQ[hi][wv]=qq; }
    __syncthreads();
    float S = redS[hi][0]+redS[hi][1];
    float Q = redQ[hi][0]+redQ[hi][1];
    float mu  = S/(float)D_MODEL;
    float var = Q/(float)D_MODEL - mu*mu;
    float inv = rsqrtf(var + EPS);
    size_t base = (size_t)tok*D_MODEL + d;
    float4 h4 = *(const float4*)(h + base);
    float4 g4 = *(const float4*)(g + d);
    float4 b4 = *(const float4*)(bb + d);
    h4.x += (v0-mu)*inv*g4.x + b4.x;
    h4.y += (v1-mu)*inv*g4.y + b4.y;
    h4.z += (v2-mu)*inv*g4.z + b4.z;
    h4.w += (v3-mu)*inv*g4.w + b4.w;
    *(float4*)(h + base) = h4;
    bf16 o4[4] = { f2b(h4.x), f2b(h4.y), f2b(h4.z), f2b(h4.w) };
    *(uint2*)(hb + base) = *(uint2*)&o4[0];
}

// ---------------- masked mean-pool over s ----------------
__global__ __launch_bounds__(256) void k_pool(const float* __restrict__ h,
        float* __restrict__ pooled) {
    int b = blockIdx.x, t = threadIdx.x;
    __shared__ float ps[64][4];
    __shared__ float pm[64];
    __shared__ float cntS;
    {
        int s = t >> 2, qq = t & 3;
        const float4* row = (const float4*)(h + ((size_t)b*SEQ + s)*D_MODEL + qq*128);
        float acc = 0;
        #pragma unroll 8
        for (int e=0;e<32;e++) { float4 f = row[e]; acc += f.x+f.y+f.z+f.w; }
        ps[s][qq] = acc;
    }
    __syncthreads();
    if (t < 64) pm[t] = (ps[t][0]+ps[t][1]+ps[t][2]+ps[t][3]) != 0.f ? 1.f : 0.f;
    __syncthreads();
    if (t == 0) { float c=0; for (int s2=0;s2<64;s2++) c+=pm[s2]; cntS = fmaxf(c,1.f); }
    __syncthreads();
    float cnt = cntS;
    #pragma unroll
    for (int rep=0;rep<2;rep++) {
        int d = t + rep*256;
        float acc = 0;
        for (int s2=0;s2<64;s2++) acc += h[((size_t)b*SEQ+s2)*D_MODEL + d] * pm[s2];
        pooled[(size_t)b*D_MODEL + d] = acc / cnt;
    }
}

// ---------------- fc1(relu) + fc2 ----------------
__global__ __launch_bounds__(128) void k_fc(const float* __restrict__ pooled,
        const float* __restrict__ w1, const float* __restrict__ b1,
        const float* __restrict__ w2, const float* __restrict__ b2,
        float* __restrict__ out) {
    int b = blockIdx.x, j = threadIdx.x;
    __shared__ float hid[FC_HID];
    const float* p  = pooled + (size_t)b*D_MODEL;
    const float* wr = w1 + (size_t)j*D_MODEL;
    float acc = b1[j];
    for (int d=0; d<D_MODEL; d+=4)
        acc += p[d]*wr[d] + p[d+1]*wr[d+1] + p[d+2]*wr[d+2] + p[d+3]*wr[d+3];
    hid[j] = fmaxf(acc, 0.f);
    __syncthreads();
    if (j < 2) {
        float o = b2[j];
        for (int k=0;k<FC_HID;k++) o += hid[k]*w2[j*FC_HID+k];
        out[b*2 + j] = o;
    }
}

extern "C" void kernel_launch(void* const* d_in, const int* in_sizes, int n_in,
                              void* d_out, int out_size, void* d_ws, size_t ws_size,
                              hipStream_t stream) {
    (void)in_sizes; (void)n_in; (void)out_size;
    const int*   x        = (const int*)  d_in[0];
    const float* emb      = (const float*)d_in[1];
    const float* pos      = (const float*)d_in[2];
    const float* in_proj  = (const float*)d_in[3];
    const float* conv_w   = (const float*)d_in[4];
    const float* conv_b   = (const float*)d_in[5];
    const float* dt_bias  = (const float*)d_in[6];
    const float* A_log    = (const float*)d_in[7];
    const float* D_skip   = (const float*)d_in[8];
    const float* norm_w   = (const float*)d_in[9];
    const float* out_proj = (const float*)d_in[10];
    const float* ln_g     = (const float*)d_in[11];
    const float* ln_b     = (const float*)d_in[12];
    const float* fc1_w    = (const float*)d_in[13];
    const float* fc1_b    = (const float*)d_in[14];
    const float* fc2_w    = (const float*)d_in[15];
    const float* fc2_b    = (const float*)d_in[16];
    float* out = (float*)d_out;

    // allow 150528 B dynamic LDS for fused SSD (idempotent, deterministic)
    const int SSD_LDS = 64*YPITCH*2 + 2*9216;     // 150528
    (void)hipFuncSetAttribute((const void*)k_ssd,
            hipFuncAttributeMaxDynamicSharedMemorySize, SSD_LDS);

    // ---- persistent region ----
    const size_t H_B   = (size_t)NTOK * D_MODEL * 4;     // 64 MB f32 h
    const size_t HB_B  = (size_t)NTOK * D_MODEL * 2;     // 32 MB bf16 shadow
    const size_t WPI_B = (size_t)NPAD * D_MODEL * 2;     // per layer 2.49 MB
    const size_t WPO_B = (size_t)D_MODEL * D_INNER * 2;  // per layer 1 MB
    const size_t PBASE = H_B + HB_B + NLAYERS*(WPI_B + WPO_B);

    // transients per token: z 2048 + xbcc 2560 + ybuf 2048 + dt/cum 128
    const size_t PER_TOK = 2048 + 2560 + 2048 + 128;     // 6784 B
    int CB = BATCH;
    while (CB > 8 && PBASE + (size_t)CB*SEQ*PER_TOK > ws_size) CB >>= 1;
    const int CT = CB * SEQ;
    const int NC = BATCH / CB;

    char* ws = (char*)d_ws;
    float* h    = (float*)(ws);
    bf16*  hb   = (bf16*) (ws + H_B);
    bf16*  wpi  = (bf16*) (ws + H_B + HB_B);                   // [NLAYERS][NPAD][512]
    bf16*  wpo  = (bf16*) (ws + H_B + HB_B + NLAYERS*WPI_B);   // [NLAYERS][512][1024]
    char*  tr   = ws + PBASE;
    bf16*  zbuf = (bf16*) (tr);                                // CT*1024
    bf16*  xbcc = (bf16*) (tr + (size_t)CT*2048);              // CT*1280
    bf16*  ybuf = (bf16*) (tr + (size_t)CT*(2048+2560));       // CT*1024
    float* dt   = (float*)(tr + (size_t)CT*(2048+2560+2048));  // [16][CT]
    float* cum  = dt + (size_t)CT*NHEADS;
    bf16*  tmp  = xbcc;                 // alias: xbcc dead after k_ssd
    float* pooled = (float*)tr;

    // weight conversion (both layers, once per launch)
    for (int l = 0; l < NLAYERS; l++) {
        int t8i = NPAD*D_MODEL/8;
        k_cvtw<<<(t8i+255)/256, 256, 0, stream>>>(in_proj + (size_t)l*D_IN_PROJ*D_MODEL,
                wpi + (size_t)l*NPAD*D_MODEL, D_IN_PROJ, D_MODEL, t8i);
        int t8o = D_MODEL*D_INNER/8;
        k_cvtw<<<(t8o+255)/256, 256, 0, stream>>>(out_proj + (size_t)l*D_MODEL*D_INNER,
                wpo + (size_t)l*D_MODEL*D_INNER, D_MODEL, D_INNER, t8o);
    }

    k_embed<<<(NTOK*128)/256, 256, 0, stream>>>(x, emb, pos, h, hb);

    const int NBX_I = NPAD/128;     // 19
    const int NBX_O = D_MODEL/128;  // 4

    for (int l = 0; l < NLAYERS; l++) {
        const bf16* wi = wpi + (size_t)l*NPAD*D_MODEL;
        const bf16* wo = wpo + (size_t)l*D_MODEL*D_INNER;
        for (int c = 0; c < NC; c++) {
            const int tok0 = c * CT;
            float* hc  = h  + (size_t)tok0 * D_MODEL;
            bf16*  hbc = hb + (size_t)tok0 * D_MODEL;
            k_gemm128<1,512><<<(CT/128)*NBX_I, 256, 0, stream>>>(hbc, wi, zbuf,
                    xbcc, dt, cum,
                    conv_w + (size_t)l*CONV_DIM*D_CONV, conv_b + (size_t)l*CONV_DIM,
                    dt_bias + l*NHEADS, A_log + l*NHEADS,
                    NPAD, NBX_I, CT);
            k_ssd<<<CB, 256, SSD_LDS, stream>>>(xbcc, dt, cum, D_skip + l*NHEADS,
                    zbuf, norm_w + (size_t)l*D_INNER, ybuf, CT);
            k_gemm128<0,1024><<<(CT/128)*NBX_O, 256, 0, stream>>>(ybuf, wo, tmp,
                    nullptr, nullptr, nullptr, nullptr, nullptr, nullptr, nullptr,
                    D_MODEL, NBX_O, CT);
            k_resln<<<CT/2, 256, 0, stream>>>(hc, hbc, tmp, ln_g + l*D_MODEL, ln_b + l*D_MODEL);
        }
    }

    k_pool<<<BATCH, 256, 0, stream>>>(h, pooled);
    k_fc<<<BATCH, FC_HID, 0, stream>>>(pooled, fc1_w, fc1_b, fc2_w, fc2_b, out);
}

// Round 15
// 596.407 us; speedup vs baseline: 1.2825x; 1.1179x over previous
//
#include <hip/hip_runtime.h>
#include <hip/hip_bf16.h>

// ---- problem constants ----
#define D_MODEL   512
#define D_STATE   128
#define D_CONV    4
#define HEADDIM   64
#define NLAYERS   2
#define D_INNER   1024
#define NHEADS    16
#define CONV_DIM  1280          // D_INNER + 2*D_STATE
#define D_IN_PROJ 2320          // 2*D_INNER + 2*D_STATE + NHEADS
#define NPAD      2432          // D_IN_PROJ padded to 128
#define SEQ       64
#define BATCH     512
#define NTOK      (BATCH*SEQ)   // 32768
#define FC_HID    128
#define EPS       1e-5f
#define YPITCH    1032          // D_INNER + 8 (LDS row pitch, 16B-aligned)

using bf16 = __hip_bfloat16;
typedef __bf16 bf16x8 __attribute__((ext_vector_type(8)));
typedef float  f32x4  __attribute__((ext_vector_type(4)));

__device__ __forceinline__ float b2f(bf16 v)  { return __bfloat162float(v); }
__device__ __forceinline__ bf16  f2b(float v) { return __float2bfloat16(v); }
__device__ __forceinline__ float bflo(unsigned u){ return __builtin_bit_cast(float, u << 16); }
__device__ __forceinline__ float bfhi(unsigned u){ return __builtin_bit_cast(float, u & 0xffff0000u); }

__device__ __forceinline__ void gl_lds16(const void* g, void* l) {
    __builtin_amdgcn_global_load_lds((const __attribute__((address_space(1))) void*)g,
                                     (__attribute__((address_space(3))) void*)l, 16, 0, 0);
}

// ---------------- embedding: hb = bf16(emb[x]+pos)  (bf16 residual stream) ----------------
__global__ __launch_bounds__(256) void k_embed(const int* __restrict__ x,
        const float* __restrict__ emb, const float* __restrict__ pos,
        bf16* __restrict__ hb) {
    int idx = blockIdx.x*256 + threadIdx.x;     // NTOK*128
    int d   = (idx & 127) * 4;
    int tok = idx >> 7;
    int s   = tok & (SEQ-1);
    int v   = x[tok];
    float4 e4 = *(const float4*)(emb + (size_t)v*D_MODEL + d);
    float4 p4 = *(const float4*)(pos + (size_t)s*D_MODEL + d);
    bf16 o[4] = { f2b(e4.x+p4.x), f2b(e4.y+p4.y), f2b(e4.z+p4.z), f2b(e4.w+p4.w) };
    *(uint2*)(hb + (size_t)tok*D_MODEL + d) = *(uint2*)&o[0];
}

// ---------------- weight convert f32 -> bf16, zero-padded rows ----------------
__global__ __launch_bounds__(256) void k_cvtw(const float* __restrict__ src,
        bf16* __restrict__ dst, int R, int Kc, int total8) {
    int idx = blockIdx.x*256 + threadIdx.x;
    if (idx >= total8) return;
    int e0 = idx*8;
    int r = e0 / Kc, c = e0 % Kc;
    bf16 tb[8];
    if (r < R) {
        float4 f0 = *(const float4*)(src + (size_t)r*Kc + c);
        float4 f1 = *(const float4*)(src + (size_t)r*Kc + c + 4);
        tb[0]=f2b(f0.x); tb[1]=f2b(f0.y); tb[2]=f2b(f0.z); tb[3]=f2b(f0.w);
        tb[4]=f2b(f1.x); tb[5]=f2b(f1.y); tb[6]=f2b(f1.z); tb[7]=f2b(f1.w);
    } else {
        #pragma unroll
        for (int e=0;e<8;e++) tb[e] = f2b(0.f);
    }
    *(uint4*)(dst + (size_t)r*Kc + c) = *(uint4*)&tb[0];
}

// ---------------- GEMM 128x128 (round-7/14 best config: 64KB dbuf, issue-early, setprio) ----------------
// FUSE=1: in_proj epilogue (z / conv+silu / dt-scan). FUSE=0: plain store.
template<int FUSE, int KDIM>
__global__ __launch_bounds__(256) void k_gemm128(const bf16* __restrict__ A,
        const bf16* __restrict__ B, bf16* __restrict__ C,
        bf16* __restrict__ xbcc, float* __restrict__ dt, float* __restrict__ cum,
        const float* __restrict__ cw, const float* __restrict__ cb,
        const float* __restrict__ dt_bias, const float* __restrict__ A_log,
        int Nout, int nbx, int ctok)
{
    constexpr int NT = KDIM / 64;
    __shared__ __align__(16) char lds[65536];      // 2 buffers x (A 16K + B 16K)
    bf16* Cs = (bf16*)lds;                         // epilogue repack alias [128][136]

    // bijective XCD swizzle (m204)
    const int nwg = gridDim.x;
    const int q = nwg >> 3, r = nwg & 7;
    const int xcd = blockIdx.x & 7, loc = blockIdx.x >> 3;
    const int wg = ((xcd < r) ? xcd*(q+1) : r*(q+1) + (xcd-r)*q) + loc;
    const int m0 = (wg / nbx) * 128;
    const int n0 = (wg % nbx) * 128;

    const int t = threadIdx.x;
    const int wid = t >> 6, lane = t & 63;
    const int lr = lane & 15, lg = lane >> 4;
    const int wm = (wid >> 1)*64, wn = (wid & 1)*64;
    const int srow = wid*32;
    const int sr   = lane >> 3;                    // row-in-chunk 0..7
    const int scol = ((lane & 7) ^ sr) * 8;        // pre-swizzled source slot

    const bf16* Abase = A + (size_t)(m0 + srow + sr)*KDIM + scol;
    const bf16* Bbase = B + (size_t)(n0 + srow + sr)*KDIM + scol;

    f32x4 acc[4][4] = {};
    char* bc = lds;             // compute buffer
    char* bn = lds + 32768;     // staging buffer

    auto STAGE = [&](char* buf, int kk) {
        #pragma unroll
        for (int c = 0; c < 4; c++) {
            gl_lds16(Abase + (size_t)(c*8)*KDIM + kk, buf + (srow + c*8)*128);
            gl_lds16(Bbase + (size_t)(c*8)*KDIM + kk, buf + 16384 + (srow + c*8)*128);
        }
    };

    STAGE(bc, 0);
    asm volatile("s_waitcnt vmcnt(0)" ::: "memory");
    __builtin_amdgcn_s_barrier();

    #pragma unroll
    for (int kt = 0; kt < NT; kt++) {
        if (kt + 1 < NT) STAGE(bn, (kt+1)*64);     // issue-early: lands under MFMA
        #pragma unroll
        for (int ks = 0; ks < 64; ks += 32) {
            bf16x8 a[4], b[4];
            #pragma unroll
            for (int mi=0;mi<4;mi++) {
                int ra = wm + mi*16 + lr;
                a[mi] = *(const bf16x8*)(bc + ra*128 + ((((ks>>3)+lg) ^ (ra&7))<<4));
            }
            #pragma unroll
            for (int ni=0;ni<4;ni++) {
                int rb = wn + ni*16 + lr;
                b[ni] = *(const bf16x8*)(bc + 16384 + rb*128 + ((((ks>>3)+lg) ^ (rb&7))<<4));
            }
            __builtin_amdgcn_s_setprio(1);
            #pragma unroll
            for (int mi=0;mi<4;mi++)
                #pragma unroll
                for (int ni=0;ni<4;ni++)
                    acc[mi][ni] = __builtin_amdgcn_mfma_f32_16x16x32_bf16(a[mi], b[ni], acc[mi][ni], 0,0,0);
            __builtin_amdgcn_s_setprio(0);
        }
        asm volatile("s_waitcnt vmcnt(0)" ::: "memory");   // this iter's stage: hidden
        __builtin_amdgcn_s_barrier();
        char* tb2 = bc; bc = bn; bn = tb2;
    }
    __builtin_amdgcn_sched_barrier(0);

    // repack C tile into LDS (bank-safe: stride 136) — staging buffers dead
    #pragma unroll
    for (int mi=0;mi<4;mi++)
        #pragma unroll
        for (int ni=0;ni<4;ni++)
            #pragma unroll
            for (int rr=0;rr<4;rr++)
                Cs[(wm+mi*16+lg*4+rr)*136 + wn+ni*16+lr] = f2b(acc[mi][ni][rr]);
    __syncthreads();

    const int rsub = t >> 4;            // 0..15
    const int c8   = (t & 15) * 8;      // constant per thread across store loop

    if (FUSE == 0 || n0 < 1024) {
        const int strd = (FUSE == 0) ? Nout : 1024;
        #pragma unroll
        for (int it = 0; it < 8; it++) {
            int row = it*16 + rsub;
            *(uint4*)(C + (size_t)(m0+row)*strd + n0 + c8) = *(const uint4*)&Cs[row*136 + c8];
        }
    } else if (n0 < 2304) {
        // depthwise causal conv + silu -> xbcc
        const int cbase = n0 - 1024 + c8;
        float4 wreg[8]; float bias[8];
        #pragma unroll
        for (int e=0;e<8;e++) wreg[e] = *(const float4*)(cw + (size_t)(cbase+e)*4);
        {
            float4 b0 = *(const float4*)(cb + cbase);
            float4 b1 = *(const float4*)(cb + cbase + 4);
            bias[0]=b0.x; bias[1]=b0.y; bias[2]=b0.z; bias[3]=b0.w;
            bias[4]=b1.x; bias[5]=b1.y; bias[6]=b1.z; bias[7]=b1.w;
        }
        #pragma unroll
        for (int it = 0; it < 8; it++) {
            int row = it*16 + rsub;
            int sl  = row & (SEQ-1);
            float m3 = (sl >= 3) ? 1.f : 0.f;
            float m2 = (sl >= 2) ? 1.f : 0.f;
            float m1 = (sl >= 1) ? 1.f : 0.f;
            const bf16* sm3 = &Cs[(row-3)*136 + c8];
            const bf16* sm2 = &Cs[(row-2)*136 + c8];
            const bf16* sm1 = &Cs[(row-1)*136 + c8];
            const bf16* sm0 = &Cs[(row  )*136 + c8];
            float a[8];
            #pragma unroll
            for (int e=0;e<8;e++) {
                a[e] = bias[e]
                     + m3 * b2f(sm3[e]) * wreg[e].x
                     + m2 * b2f(sm2[e]) * wreg[e].y
                     + m1 * b2f(sm1[e]) * wreg[e].z
                     +      b2f(sm0[e]) * wreg[e].w;
            }
            bf16 outv[8];
            #pragma unroll
            for (int e=0;e<8;e++) outv[e] = f2b(a[e] / (1.f + __expf(-a[e])));
            *(uint4*)(xbcc + (size_t)(m0+row)*CONV_DIM + cbase) = *(uint4*)&outv[0];
        }
    } else {
        // dt tile: softplus + cumsum scan over each sequence, write dt/cum f32
        for (int p = wid; p < 32; p += 4) {       // (seq-in-tile, head)
            int sq = p >> 4, head = p & 15;
            float raw = b2f(Cs[(sq*64 + lane)*136 + head]) + dt_bias[head];
            float dval = (raw > 20.f) ? raw : log1pf(__expf(raw));
            float Ah = -__expf(A_log[head]);
            float cc = dval * Ah;
            #pragma unroll
            for (int o=1;o<64;o<<=1) { float v = __shfl_up(cc, o); if (lane >= o) cc += v; }
            int tok = m0 + sq*64 + lane;
            dt [(size_t)head*ctok + tok] = dval;
            cum[(size_t)head*ctok + tok] = cc;
        }
    }
}

// ---------------- SSD core v3c: batch/block, fused gate/RMS, in-place into zbuf ----------------
// One block per batch: 16 heads serially (scores in REGISTERS); per-head y -> LDS yb.
// Gate/RMS phase wave-per-token (coalesced); output OVERWRITES zbuf in place
// (each thread rewrites exactly the z elements it read) -> ybuf buffer eliminated.
__global__ __launch_bounds__(256) void k_ssd(const bf16* __restrict__ xbcc,
        const float* __restrict__ dt, const float* __restrict__ cum,
        const float* __restrict__ Dskip, bf16* zio,
        const float* __restrict__ nw, int ctok) {
    extern __shared__ __align__(16) char sm[];
    bf16* yb  = (bf16*)sm;                                   // [64][YPITCH] 132096 B
    bf16* Wb  = (bf16*)(sm + 64*YPITCH*2);                   // [64][72] 9216 B
    bf16* xsT = (bf16*)(sm + 64*YPITCH*2 + 9216);            // [64][72] 9216 B
    const int b = blockIdx.x;
    const int t = threadIdx.x;
    const size_t tokbase = (size_t)b*SEQ;
    const int lane = t & 63, lr = lane & 15, lg = lane >> 4;
    const int w = t >> 6;
    const int i0 = w*16;

    // scores kept in registers: sacc[jt][rr] = scores[i0+lg*4+rr][jt*16+lr]
    f32x4 sacc[4] = {};
    {
        const bf16* Cbase = xbcc + tokbase*CONV_DIM + D_INNER + D_STATE;
        const bf16* Bbase = xbcc + tokbase*CONV_DIM + D_INNER;
        #pragma unroll
        for (int ks = 0; ks < D_STATE; ks += 32) {
            bf16x8 af = *(const bf16x8*)(Cbase + (size_t)(i0+lr)*CONV_DIM + ks + lg*8);
            #pragma unroll
            for (int jt = 0; jt < 4; jt++) {
                bf16x8 bfr = *(const bf16x8*)(Bbase + (size_t)(jt*16+lr)*CONV_DIM + ks + lg*8);
                sacc[jt] = __builtin_amdgcn_mfma_f32_16x16x32_bf16(af, bfr, sacc[jt], 0,0,0);
            }
        }
    }

    for (int hh = 0; hh < NHEADS; hh++) {
        const size_t cbase = (size_t)hh*ctok + tokbase;
        __syncthreads();   // prev head's MFMA readers done -> Wb/xsT reusable

        // stage xsT (transpose xs)
        #pragma unroll
        for (int cc = 0; cc < 2; cc++) {
            int ch = cc*256 + t;
            int rr = ch >> 3, c8 = (ch & 7)*8;
            uint4 v = *(const uint4*)(xbcc + (tokbase + rr)*CONV_DIM + hh*HEADDIM + c8);
            const bf16* pv = (const bf16*)&v;
            #pragma unroll
            for (int e=0;e<8;e++) xsT[(c8+e)*72 + rr] = pv[e];
        }
        // build Wb straight from register scores
        {
            float cum_i[4], cum_j[4], dt_j[4];
            #pragma unroll
            for (int rr=0;rr<4;rr++) cum_i[rr] = cum[cbase + i0 + lg*4 + rr];
            #pragma unroll
            for (int jt=0;jt<4;jt++) { int j = jt*16+lr; cum_j[jt]=cum[cbase+j]; dt_j[jt]=dt[cbase+j]; }
            #pragma unroll
            for (int jt=0;jt<4;jt++)
                #pragma unroll
                for (int rr=0;rr<4;rr++) {
                    int i = i0 + lg*4 + rr, j = jt*16 + lr;
                    float wv = (j <= i) ? sacc[jt][rr] * __expf(cum_i[rr]-cum_j[jt]) * dt_j[jt] : 0.f;
                    Wb[i*72 + j] = f2b(wv);
                }
        }
        __syncthreads();

        // y = Wb @ xsT^T + Dskip*xs  -> yb[:, hh*64..]
        {
            float dsk = Dskip[hh];
            f32x4 yacc[4] = {};
            #pragma unroll
            for (int ks = 0; ks < 64; ks += 32) {
                bf16x8 a = *(const bf16x8*)&Wb[(w*16 + lr)*72 + ks + lg*8];
                #pragma unroll
                for (int n=0; n<4; n++) {
                    bf16x8 bb = *(const bf16x8*)&xsT[(n*16 + lr)*72 + ks + lg*8];
                    yacc[n] = __builtin_amdgcn_mfma_f32_16x16x32_bf16(a, bb, yacc[n], 0,0,0);
                }
            }
            #pragma unroll
            for (int n=0; n<4; n++)
                #pragma unroll
                for (int rr=0; rr<4; rr++) {
                    int row = w*16 + lg*4 + rr;
                    int col = n*16 + lr;
                    yb[row*YPITCH + hh*HEADDIM + col] = f2b(yacc[n][rr] + dsk * b2f(xsT[col*72 + row]));
                }
        }
    }
    __syncthreads();   // yb complete

    // ---- fused gate + RMS-norm, wave-per-token, in-place into zio ----
    for (int pass = 0; pass < 16; pass++) {
        const int tok = pass*4 + w;
        const int d0  = lane*16;                   // 16 elements per lane
        bf16* zrow        = zio + (tokbase + tok)*D_INNER + d0;
        const bf16* ybrow = yb + tok*YPITCH + d0;
        uint4 yv0 = *(const uint4*)(ybrow);
        uint4 yv1 = *(const uint4*)(ybrow + 8);
        uint4 zv0 = *(const uint4*)(zrow);
        uint4 zv1 = *(const uint4*)(zrow + 8);
        const unsigned* yu0 = (const unsigned*)&yv0;
        const unsigned* yu1 = (const unsigned*)&yv1;
        const unsigned* zu0 = (const unsigned*)&zv0;
        const unsigned* zu1 = (const unsigned*)&zv1;
        float g[16]; float ss = 0.f;
        #pragma unroll
        for (int e=0;e<4;e++) {
            float y0 = bflo(yu0[e]), y1 = bfhi(yu0[e]);
            float z0 = bflo(zu0[e]), z1 = bfhi(zu0[e]);
            float g0 = y0 * z0 / (1.f + __expf(-z0));
            float g1 = y1 * z1 / (1.f + __expf(-z1));
            g[2*e] = g0; g[2*e+1] = g1;
            ss += g0*g0 + g1*g1;
            float y2 = bflo(yu1[e]), y3 = bfhi(yu1[e]);
            float z2 = bflo(zu1[e]), z3 = bfhi(zu1[e]);
            float g2 = y2 * z2 / (1.f + __expf(-z2));
            float g3 = y3 * z3 / (1.f + __expf(-z3));
            g[8+2*e] = g2; g[8+2*e+1] = g3;
            ss += g2*g2 + g3*g3;
        }
        #pragma unroll
        for (int o=32;o>0;o>>=1) ss += __shfl_xor(ss, o);
        float scale = rsqrtf(ss/(float)D_INNER + EPS);
        bf16 outv[16];
        #pragma unroll
        for (int e=0;e<16;e++) outv[e] = f2b(g[e] * scale * nw[d0+e]);
        *(uint4*)zrow     = *(uint4*)&outv[0];
        *(uint4*)(zrow+8) = *(uint4*)&outv[8];
    }
}

// ---------------- hb += layernorm(tmp)*g + b (bf16 residual, f32 math) ----------------
__global__ __launch_bounds__(256) void k_resln(bf16* __restrict__ hb,
        const bf16* __restrict__ tmp,
        const float* __restrict__ g, const float* __restrict__ bb) {
    int tok = blockIdx.x*2 + (threadIdx.x >> 7);
    int t   = threadIdx.x & 127;
    int hi  = threadIdx.x >> 7, wv = (threadIdx.x >> 6) & 1;
    __shared__ float redS[2][2], redQ[2][2];
    int d = t*4;
    uint2 u2 = *(const uint2*)(tmp + (size_t)tok*D_MODEL + d);
    const unsigned* uu = (const unsigned*)&u2;
    float v0 = bflo(uu[0]), v1 = bfhi(uu[0]), v2 = bflo(uu[1]), v3 = bfhi(uu[1]);
    float s = v0+v1+v2+v3;
    float qq = v0*v0+v1*v1+v2*v2+v3*v3;
    for (int o=32;o>0;o>>=1){ s += __shfl_down(s,o); qq += __shfl_down(qq,o); }
    if ((threadIdx.x & 63) == 0){ redS[hi][wv]=s; redQ[hi][wv]=qq; }
    __syncthreads();
    float S = redS[hi][0]+redS[hi][1];
    float Q = redQ[hi][0]+redQ[hi][1];
    float mu  = S/(float)D_MODEL;
    float var = Q/(float)D_MODEL - mu*mu;
    float inv = rsqrtf(var + EPS);
    size_t base = (size_t)tok*D_MODEL + d;
    uint2 h2 = *(const uint2*)(hb + base);
    const unsigned* hu = (const unsigned*)&h2;
    float4 g4 = *(const float4*)(g + d);
    float4 b4 = *(const float4*)(bb + d);
    float h0 = bflo(hu[0]) + (v0-mu)*inv*g4.x + b4.x;
    float h1 = bfhi(hu[0]) + (v1-mu)*inv*g4.y + b4.y;
    float h2f = bflo(hu[1]) + (v2-mu)*inv*g4.z + b4.z;
    float h3 = bfhi(hu[1]) + (v3-mu)*inv*g4.w + b4.w;
    bf16 o4[4] = { f2b(h0), f2b(h1), f2b(h2f), f2b(h3) };
    *(uint2*)(hb + base) = *(uint2*)&o4[0];
}

// ---------------- masked mean-pool over s (bf16 hb) ----------------
__global__ __launch_bounds__(256) void k_pool(const bf16* __restrict__ hb,
        float* __restrict__ pooled) {
    int b = blockIdx.x, t = threadIdx.x;
    __shared__ float ps[64][4];
    __shared__ float pm[64];
    __shared__ float cntS;
    {
        int s = t >> 2, qq = t & 3;
        const bf16* row = hb + ((size_t)b*SEQ + s)*D_MODEL + qq*128;
        float acc = 0;
        #pragma unroll
        for (int e=0;e<16;e++) {
            uint4 v = *(const uint4*)(row + e*8);
            const unsigned* vu = (const unsigned*)&v;
            #pragma unroll
            for (int k=0;k<4;k++) acc += bflo(vu[k]) + bfhi(vu[k]);
        }
        ps[s][qq] = acc;
    }
    __syncthreads();
    if (t < 64) pm[t] = (ps[t][0]+ps[t][1]+ps[t][2]+ps[t][3]) != 0.f ? 1.f : 0.f;
    __syncthreads();
    if (t == 0) { float c=0; for (int s2=0;s2<64;s2++) c+=pm[s2]; cntS = fmaxf(c,1.f); }
    __syncthreads();
    float cnt = cntS;
    #pragma unroll
    for (int rep=0;rep<2;rep++) {
        int d = t + rep*256;
        float acc = 0;
        for (int s2=0;s2<64;s2++)
            acc += b2f(hb[((size_t)b*SEQ+s2)*D_MODEL + d]) * pm[s2];
        pooled[(size_t)b*D_MODEL + d] = acc / cnt;
    }
}

// ---------------- fc1(relu) + fc2 ----------------
__global__ __launch_bounds__(128) void k_fc(const float* __restrict__ pooled,
        const float* __restrict__ w1, const float* __restrict__ b1,
        const float* __restrict__ w2, const float* __restrict__ b2,
        float* __restrict__ out) {
    int b = blockIdx.x, j = threadIdx.x;
    __shared__ float hid[FC_HID];
    const float* p  = pooled + (size_t)b*D_MODEL;
    const float* wr = w1 + (size_t)j*D_MODEL;
    float acc = b1[j];
    for (int d=0; d<D_MODEL; d+=4)
        acc += p[d]*wr[d] + p[d+1]*wr[d+1] + p[d+2]*wr[d+2] + p[d+3]*wr[d+3];
    hid[j] = fmaxf(acc, 0.f);
    __syncthreads();
    if (j < 2) {
        float o = b2[j];
        for (int k=0;k<FC_HID;k++) o += hid[k]*w2[j*FC_HID+k];
        out[b*2 + j] = o;
    }
}

extern "C" void kernel_launch(void* const* d_in, const int* in_sizes, int n_in,
                              void* d_out, int out_size, void* d_ws, size_t ws_size,
                              hipStream_t stream) {
    (void)in_sizes; (void)n_in; (void)out_size;
    const int*   x        = (const int*)  d_in[0];
    const float* emb      = (const float*)d_in[1];
    const float* pos      = (const float*)d_in[2];
    const float* in_proj  = (const float*)d_in[3];
    const float* conv_w   = (const float*)d_in[4];
    const float* conv_b   = (const float*)d_in[5];
    const float* dt_bias  = (const float*)d_in[6];
    const float* A_log    = (const float*)d_in[7];
    const float* D_skip   = (const float*)d_in[8];
    const float* norm_w   = (const float*)d_in[9];
    const float* out_proj = (const float*)d_in[10];
    const float* ln_g     = (const float*)d_in[11];
    const float* ln_b     = (const float*)d_in[12];
    const float* fc1_w    = (const float*)d_in[13];
    const float* fc1_b    = (const float*)d_in[14];
    const float* fc2_w    = (const float*)d_in[15];
    const float* fc2_b    = (const float*)d_in[16];
    float* out = (float*)d_out;

    // allow 150528 B dynamic LDS for fused SSD (idempotent, deterministic)
    const int SSD_LDS = 64*YPITCH*2 + 2*9216;     // 150528
    (void)hipFuncSetAttribute((const void*)k_ssd,
            hipFuncAttributeMaxDynamicSharedMemorySize, SSD_LDS);

    // ---- persistent region: bf16 residual stream + bf16 weights ----
    const size_t HB_B  = (size_t)NTOK * D_MODEL * 2;     // 32 MB bf16 residual
    const size_t WPI_B = (size_t)NPAD * D_MODEL * 2;     // per layer 2.49 MB
    const size_t WPO_B = (size_t)D_MODEL * D_INNER * 2;  // per layer 1 MB
    const size_t PBASE = HB_B + NLAYERS*(WPI_B + WPO_B); // ~39.3 MB

    // transients per token: z 2048 + xbcc 2560 + dt/cum 128 (ybuf eliminated: in-place)
    const size_t PER_TOK = 2048 + 2560 + 128;            // 4736 B
    int CB = BATCH;
    while (CB > 8 && PBASE + (size_t)CB*SEQ*PER_TOK > ws_size) CB >>= 1;
    const int CT = CB * SEQ;
    const int NC = BATCH / CB;

    char* ws = (char*)d_ws;
    bf16*  hb   = (bf16*) (ws);
    bf16*  wpi  = (bf16*) (ws + HB_B);                   // [NLAYERS][NPAD][512]
    bf16*  wpo  = (bf16*) (ws + HB_B + NLAYERS*WPI_B);   // [NLAYERS][512][1024]
    char*  tr   = ws + PBASE;
    bf16*  zbuf = (bf16*) (tr);                          // CT*1024 (z, then gated y in place)
    bf16*  xbcc = (bf16*) (tr + (size_t)CT*2048);        // CT*1280
    float* dt   = (float*)(tr + (size_t)CT*(2048+2560)); // [16][CT]
    float* cum  = dt + (size_t)CT*NHEADS;
    bf16*  tmp  = xbcc;                 // alias: xbcc dead after k_ssd
    float* pooled = (float*)tr;

    // weight conversion (both layers, once per launch)
    for (int l = 0; l < NLAYERS; l++) {
        int t8i = NPAD*D_MODEL/8;
        k_cvtw<<<(t8i+255)/256, 256, 0, stream>>>(in_proj + (size_t)l*D_IN_PROJ*D_MODEL,
                wpi + (size_t)l*NPAD*D_MODEL, D_IN_PROJ, D_MODEL, t8i);
        int t8o = D_MODEL*D_INNER/8;
        k_cvtw<<<(t8o+255)/256, 256, 0, stream>>>(out_proj + (size_t)l*D_MODEL*D_INNER,
                wpo + (size_t)l*D_MODEL*D_INNER, D_MODEL, D_INNER, t8o);
    }

    k_embed<<<(NTOK*128)/256, 256, 0, stream>>>(x, emb, pos, hb);

    const int NBX_I = NPAD/128;     // 19
    const int NBX_O = D_MODEL/128;  // 4

    for (int l = 0; l < NLAYERS; l++) {
        const bf16* wi = wpi + (size_t)l*NPAD*D_MODEL;
        const bf16* wo = wpo + (size_t)l*D_MODEL*D_INNER;
        for (int c = 0; c < NC; c++) {
            const int tok0 = c * CT;
            bf16* hbc = hb + (size_t)tok0 * D_MODEL;
            k_gemm128<1,512><<<(CT/128)*NBX_I, 256, 0, stream>>>(hbc, wi, zbuf,
                    xbcc, dt, cum,
                    conv_w + (size_t)l*CONV_DIM*D_CONV, conv_b + (size_t)l*CONV_DIM,
                    dt_bias + l*NHEADS, A_log + l*NHEADS,
                    NPAD, NBX_I, CT);
            k_ssd<<<CB, 256, SSD_LDS, stream>>>(xbcc, dt, cum, D_skip + l*NHEADS,
                    zbuf, norm_w + (size_t)l*D_INNER, CT);
            k_gemm128<0,1024><<<(CT/128)*NBX_O, 256, 0, stream>>>(zbuf, wo, tmp,
                    nullptr, nullptr, nullptr, nullptr, nullptr, nullptr, nullptr,
                    D_MODEL, NBX_O, CT);
            k_resln<<<CT/2, 256, 0, stream>>>(hbc, tmp, ln_g + l*D_MODEL, ln_b + l*D_MODEL);
        }
    }

    k_pool<<<BATCH, 256, 0, stream>>>(hb, pooled);
    k_fc<<<BATCH, FC_HID, 0, stream>>>(pooled, fc1_w, fc1_b, fc2_w, fc2_b, out);
}

// Round 16
// 589.008 us; speedup vs baseline: 1.2986x; 1.0126x over previous
//
#include <hip/hip_runtime.h>
#include <hip/hip_bf16.h>

// ---- problem constants ----
#define D_MODEL   512
#define D_STATE   128
#define D_CONV    4
#define HEADDIM   64
#define NLAYERS   2
#define D_INNER   1024
#define NHEADS    16
#define CONV_DIM  1280          // D_INNER + 2*D_STATE
#define D_IN_PROJ 2320          // 2*D_INNER + 2*D_STATE + NHEADS
#define NPAD      2432          // D_IN_PROJ padded to 128
#define SEQ       64
#define BATCH     512
#define NTOK      (BATCH*SEQ)   // 32768
#define FC_HID    128
#define EPS       1e-5f
#define YPITCH    1032          // D_INNER + 8 (LDS row pitch, 16B-aligned)

using bf16 = __hip_bfloat16;
typedef __bf16 bf16x8 __attribute__((ext_vector_type(8)));
typedef float  f32x4  __attribute__((ext_vector_type(4)));

__device__ __forceinline__ float b2f(bf16 v)  { return __bfloat162float(v); }
__device__ __forceinline__ bf16  f2b(float v) { return __float2bfloat16(v); }
__device__ __forceinline__ float bflo(unsigned u){ return __builtin_bit_cast(float, u << 16); }
__device__ __forceinline__ float bfhi(unsigned u){ return __builtin_bit_cast(float, u & 0xffff0000u); }

__device__ __forceinline__ void gl_lds16(const void* g, void* l) {
    __builtin_amdgcn_global_load_lds((const __attribute__((address_space(1))) void*)g,
                                     (__attribute__((address_space(3))) void*)l, 16, 0, 0);
}

// ---------------- embedding: hb = bf16(emb[x]+pos)  (bf16 residual stream) ----------------
__global__ __launch_bounds__(256) void k_embed(const int* __restrict__ x,
        const float* __restrict__ emb, const float* __restrict__ pos,
        bf16* __restrict__ hb) {
    int idx = blockIdx.x*256 + threadIdx.x;     // NTOK*128
    int d   = (idx & 127) * 4;
    int tok = idx >> 7;
    int s   = tok & (SEQ-1);
    int v   = x[tok];
    float4 e4 = *(const float4*)(emb + (size_t)v*D_MODEL + d);
    float4 p4 = *(const float4*)(pos + (size_t)s*D_MODEL + d);
    bf16 o[4] = { f2b(e4.x+p4.x), f2b(e4.y+p4.y), f2b(e4.z+p4.z), f2b(e4.w+p4.w) };
    *(uint2*)(hb + (size_t)tok*D_MODEL + d) = *(uint2*)&o[0];
}

// ---------------- weight convert f32 -> bf16, zero-padded rows ----------------
__global__ __launch_bounds__(256) void k_cvtw(const float* __restrict__ src,
        bf16* __restrict__ dst, int R, int Kc, int total8) {
    int idx = blockIdx.x*256 + threadIdx.x;
    if (idx >= total8) return;
    int e0 = idx*8;
    int r = e0 / Kc, c = e0 % Kc;
    bf16 tb[8];
    if (r < R) {
        float4 f0 = *(const float4*)(src + (size_t)r*Kc + c);
        float4 f1 = *(const float4*)(src + (size_t)r*Kc + c + 4);
        tb[0]=f2b(f0.x); tb[1]=f2b(f0.y); tb[2]=f2b(f0.z); tb[3]=f2b(f0.w);
        tb[4]=f2b(f1.x); tb[5]=f2b(f1.y); tb[6]=f2b(f1.z); tb[7]=f2b(f1.w);
    } else {
        #pragma unroll
        for (int e=0;e<8;e++) tb[e] = f2b(0.f);
    }
    *(uint4*)(dst + (size_t)r*Kc + c) = *(uint4*)&tb[0];
}

// ---------------- GEMM 128x128 (round-7/14 best config: 64KB dbuf, issue-early, setprio) ----------------
// FUSE=1: in_proj epilogue (z / conv+silu / dt-scan). FUSE=0: plain store.
template<int FUSE, int KDIM>
__global__ __launch_bounds__(256) void k_gemm128(const bf16* __restrict__ A,
        const bf16* __restrict__ B, bf16* __restrict__ C,
        bf16* __restrict__ xbcc, float* __restrict__ dt, float* __restrict__ cum,
        const float* __restrict__ cw, const float* __restrict__ cb,
        const float* __restrict__ dt_bias, const float* __restrict__ A_log,
        int Nout, int nbx, int ctok)
{
    constexpr int NT = KDIM / 64;
    __shared__ __align__(16) char lds[65536];      // 2 buffers x (A 16K + B 16K)
    bf16* Cs = (bf16*)lds;                         // epilogue repack alias [128][136]

    // bijective XCD swizzle (m204)
    const int nwg = gridDim.x;
    const int q = nwg >> 3, r = nwg & 7;
    const int xcd = blockIdx.x & 7, loc = blockIdx.x >> 3;
    const int wg = ((xcd < r) ? xcd*(q+1) : r*(q+1) + (xcd-r)*q) + loc;
    const int m0 = (wg / nbx) * 128;
    const int n0 = (wg % nbx) * 128;

    const int t = threadIdx.x;
    const int wid = t >> 6, lane = t & 63;
    const int lr = lane & 15, lg = lane >> 4;
    const int wm = (wid >> 1)*64, wn = (wid & 1)*64;
    const int srow = wid*32;
    const int sr   = lane >> 3;                    // row-in-chunk 0..7
    const int scol = ((lane & 7) ^ sr) * 8;        // pre-swizzled source slot

    const bf16* Abase = A + (size_t)(m0 + srow + sr)*KDIM + scol;
    const bf16* Bbase = B + (size_t)(n0 + srow + sr)*KDIM + scol;

    f32x4 acc[4][4] = {};
    char* bc = lds;             // compute buffer
    char* bn = lds + 32768;     // staging buffer

    auto STAGE = [&](char* buf, int kk) {
        #pragma unroll
        for (int c = 0; c < 4; c++) {
            gl_lds16(Abase + (size_t)(c*8)*KDIM + kk, buf + (srow + c*8)*128);
            gl_lds16(Bbase + (size_t)(c*8)*KDIM + kk, buf + 16384 + (srow + c*8)*128);
        }
    };

    STAGE(bc, 0);
    asm volatile("s_waitcnt vmcnt(0)" ::: "memory");
    __builtin_amdgcn_s_barrier();

    #pragma unroll
    for (int kt = 0; kt < NT; kt++) {
        if (kt + 1 < NT) STAGE(bn, (kt+1)*64);     // issue-early: lands under MFMA
        #pragma unroll
        for (int ks = 0; ks < 64; ks += 32) {
            bf16x8 a[4], b[4];
            #pragma unroll
            for (int mi=0;mi<4;mi++) {
                int ra = wm + mi*16 + lr;
                a[mi] = *(const bf16x8*)(bc + ra*128 + ((((ks>>3)+lg) ^ (ra&7))<<4));
            }
            #pragma unroll
            for (int ni=0;ni<4;ni++) {
                int rb = wn + ni*16 + lr;
                b[ni] = *(const bf16x8*)(bc + 16384 + rb*128 + ((((ks>>3)+lg) ^ (rb&7))<<4));
            }
            __builtin_amdgcn_s_setprio(1);
            #pragma unroll
            for (int mi=0;mi<4;mi++)
                #pragma unroll
                for (int ni=0;ni<4;ni++)
                    acc[mi][ni] = __builtin_amdgcn_mfma_f32_16x16x32_bf16(a[mi], b[ni], acc[mi][ni], 0,0,0);
            __builtin_amdgcn_s_setprio(0);
        }
        asm volatile("s_waitcnt vmcnt(0)" ::: "memory");   // this iter's stage: hidden
        __builtin_amdgcn_s_barrier();
        char* tb2 = bc; bc = bn; bn = tb2;
    }
    __builtin_amdgcn_sched_barrier(0);

    // repack C tile into LDS (bank-safe: stride 136) — staging buffers dead
    #pragma unroll
    for (int mi=0;mi<4;mi++)
        #pragma unroll
        for (int ni=0;ni<4;ni++)
            #pragma unroll
            for (int rr=0;rr<4;rr++)
                Cs[(wm+mi*16+lg*4+rr)*136 + wn+ni*16+lr] = f2b(acc[mi][ni][rr]);
    __syncthreads();

    const int rsub = t >> 4;            // 0..15
    const int c8   = (t & 15) * 8;      // constant per thread across store loop

    if (FUSE == 0 || n0 < 1024) {
        const int strd = (FUSE == 0) ? Nout : 1024;
        #pragma unroll
        for (int it = 0; it < 8; it++) {
            int row = it*16 + rsub;
            *(uint4*)(C + (size_t)(m0+row)*strd + n0 + c8) = *(const uint4*)&Cs[row*136 + c8];
        }
    } else if (n0 < 2304) {
        // depthwise causal conv + silu -> xbcc
        const int cbase = n0 - 1024 + c8;
        float4 wreg[8]; float bias[8];
        #pragma unroll
        for (int e=0;e<8;e++) wreg[e] = *(const float4*)(cw + (size_t)(cbase+e)*4);
        {
            float4 b0 = *(const float4*)(cb + cbase);
            float4 b1 = *(const float4*)(cb + cbase + 4);
            bias[0]=b0.x; bias[1]=b0.y; bias[2]=b0.z; bias[3]=b0.w;
            bias[4]=b1.x; bias[5]=b1.y; bias[6]=b1.z; bias[7]=b1.w;
        }
        #pragma unroll
        for (int it = 0; it < 8; it++) {
            int row = it*16 + rsub;
            int sl  = row & (SEQ-1);
            float m3 = (sl >= 3) ? 1.f : 0.f;
            float m2 = (sl >= 2) ? 1.f : 0.f;
            float m1 = (sl >= 1) ? 1.f : 0.f;
            const bf16* sm3 = &Cs[(row-3)*136 + c8];
            const bf16* sm2 = &Cs[(row-2)*136 + c8];
            const bf16* sm1 = &Cs[(row-1)*136 + c8];
            const bf16* sm0 = &Cs[(row  )*136 + c8];
            float a[8];
            #pragma unroll
            for (int e=0;e<8;e++) {
                a[e] = bias[e]
                     + m3 * b2f(sm3[e]) * wreg[e].x
                     + m2 * b2f(sm2[e]) * wreg[e].y
                     + m1 * b2f(sm1[e]) * wreg[e].z
                     +      b2f(sm0[e]) * wreg[e].w;
            }
            bf16 outv[8];
            #pragma unroll
            for (int e=0;e<8;e++) outv[e] = f2b(a[e] / (1.f + __expf(-a[e])));
            *(uint4*)(xbcc + (size_t)(m0+row)*CONV_DIM + cbase) = *(uint4*)&outv[0];
        }
    } else {
        // dt tile: softplus + cumsum scan over each sequence, write dt/cum f32
        for (int p = wid; p < 32; p += 4) {       // (seq-in-tile, head)
            int sq = p >> 4, head = p & 15;
            float raw = b2f(Cs[(sq*64 + lane)*136 + head]) + dt_bias[head];
            float dval = (raw > 20.f) ? raw : log1pf(__expf(raw));
            float Ah = -__expf(A_log[head]);
            float cc = dval * Ah;
            #pragma unroll
            for (int o=1;o<64;o<<=1) { float v = __shfl_up(cc, o); if (lane >= o) cc += v; }
            int tok = m0 + sq*64 + lane;
            dt [(size_t)head*ctok + tok] = dval;
            cum[(size_t)head*ctok + tok] = cc;
        }
    }
}

// ---------------- SSD core v3c: batch/block, fused gate/RMS, in-place into zbuf ----------------
__global__ __launch_bounds__(256) void k_ssd(const bf16* __restrict__ xbcc,
        const float* __restrict__ dt, const float* __restrict__ cum,
        const float* __restrict__ Dskip, bf16* zio,
        const float* __restrict__ nw, int ctok) {
    extern __shared__ __align__(16) char sm[];
    bf16* yb  = (bf16*)sm;                                   // [64][YPITCH] 132096 B
    bf16* Wb  = (bf16*)(sm + 64*YPITCH*2);                   // [64][72] 9216 B
    bf16* xsT = (bf16*)(sm + 64*YPITCH*2 + 9216);            // [64][72] 9216 B
    const int b = blockIdx.x;
    const int t = threadIdx.x;
    const size_t tokbase = (size_t)b*SEQ;
    const int lane = t & 63, lr = lane & 15, lg = lane >> 4;
    const int w = t >> 6;
    const int i0 = w*16;

    // scores kept in registers: sacc[jt][rr] = scores[i0+lg*4+rr][jt*16+lr]
    f32x4 sacc[4] = {};
    {
        const bf16* Cbase = xbcc + tokbase*CONV_DIM + D_INNER + D_STATE;
        const bf16* Bbase = xbcc + tokbase*CONV_DIM + D_INNER;
        #pragma unroll
        for (int ks = 0; ks < D_STATE; ks += 32) {
            bf16x8 af = *(const bf16x8*)(Cbase + (size_t)(i0+lr)*CONV_DIM + ks + lg*8);
            #pragma unroll
            for (int jt = 0; jt < 4; jt++) {
                bf16x8 bfr = *(const bf16x8*)(Bbase + (size_t)(jt*16+lr)*CONV_DIM + ks + lg*8);
                sacc[jt] = __builtin_amdgcn_mfma_f32_16x16x32_bf16(af, bfr, sacc[jt], 0,0,0);
            }
        }
    }

    for (int hh = 0; hh < NHEADS; hh++) {
        const size_t cbase = (size_t)hh*ctok + tokbase;
        __syncthreads();   // prev head's MFMA readers done -> Wb/xsT reusable

        // stage xsT (transpose xs)
        #pragma unroll
        for (int cc = 0; cc < 2; cc++) {
            int ch = cc*256 + t;
            int rr = ch >> 3, c8 = (ch & 7)*8;
            uint4 v = *(const uint4*)(xbcc + (tokbase + rr)*CONV_DIM + hh*HEADDIM + c8);
            const bf16* pv = (const bf16*)&v;
            #pragma unroll
            for (int e=0;e<8;e++) xsT[(c8+e)*72 + rr] = pv[e];
        }
        // build Wb straight from register scores
        {
            float cum_i[4], cum_j[4], dt_j[4];
            #pragma unroll
            for (int rr=0;rr<4;rr++) cum_i[rr] = cum[cbase + i0 + lg*4 + rr];
            #pragma unroll
            for (int jt=0;jt<4;jt++) { int j = jt*16+lr; cum_j[jt]=cum[cbase+j]; dt_j[jt]=dt[cbase+j]; }
            #pragma unroll
            for (int jt=0;jt<4;jt++)
                #pragma unroll
                for (int rr=0;rr<4;rr++) {
                    int i = i0 + lg*4 + rr, j = jt*16 + lr;
                    float wv = (j <= i) ? sacc[jt][rr] * __expf(cum_i[rr]-cum_j[jt]) * dt_j[jt] : 0.f;
                    Wb[i*72 + j] = f2b(wv);
                }
        }
        __syncthreads();

        // y = Wb @ xsT^T + Dskip*xs  -> yb[:, hh*64..]
        {
            float dsk = Dskip[hh];
            f32x4 yacc[4] = {};
            #pragma unroll
            for (int ks = 0; ks < 64; ks += 32) {
                bf16x8 a = *(const bf16x8*)&Wb[(w*16 + lr)*72 + ks + lg*8];
                #pragma unroll
                for (int n=0; n<4; n++) {
                    bf16x8 bb = *(const bf16x8*)&xsT[(n*16 + lr)*72 + ks + lg*8];
                    yacc[n] = __builtin_amdgcn_mfma_f32_16x16x32_bf16(a, bb, yacc[n], 0,0,0);
                }
            }
            #pragma unroll
            for (int n=0; n<4; n++)
                #pragma unroll
                for (int rr=0; rr<4; rr++) {
                    int row = w*16 + lg*4 + rr;
                    int col = n*16 + lr;
                    yb[row*YPITCH + hh*HEADDIM + col] = f2b(yacc[n][rr] + dsk * b2f(xsT[col*72 + row]));
                }
        }
    }
    __syncthreads();   // yb complete

    // ---- fused gate + RMS-norm, wave-per-token, in-place into zio ----
    for (int pass = 0; pass < 16; pass++) {
        const int tok = pass*4 + w;
        const int d0  = lane*16;                   // 16 elements per lane
        bf16* zrow        = zio + (tokbase + tok)*D_INNER + d0;
        const bf16* ybrow = yb + tok*YPITCH + d0;
        uint4 yv0 = *(const uint4*)(ybrow);
        uint4 yv1 = *(const uint4*)(ybrow + 8);
        uint4 zv0 = *(const uint4*)(zrow);
        uint4 zv1 = *(const uint4*)(zrow + 8);
        const unsigned* yu0 = (const unsigned*)&yv0;
        const unsigned* yu1 = (const unsigned*)&yv1;
        const unsigned* zu0 = (const unsigned*)&zv0;
        const unsigned* zu1 = (const unsigned*)&zv1;
        float g[16]; float ss = 0.f;
        #pragma unroll
        for (int e=0;e<4;e++) {
            float y0 = bflo(yu0[e]), y1 = bfhi(yu0[e]);
            float z0 = bflo(zu0[e]), z1 = bfhi(zu0[e]);
            float g0 = y0 * z0 / (1.f + __expf(-z0));
            float g1 = y1 * z1 / (1.f + __expf(-z1));
            g[2*e] = g0; g[2*e+1] = g1;
            ss += g0*g0 + g1*g1;
            float y2 = bflo(yu1[e]), y3 = bfhi(yu1[e]);
            float z2 = bflo(zu1[e]), z3 = bfhi(zu1[e]);
            float g2 = y2 * z2 / (1.f + __expf(-z2));
            float g3 = y3 * z3 / (1.f + __expf(-z3));
            g[8+2*e] = g2; g[8+2*e+1] = g3;
            ss += g2*g2 + g3*g3;
        }
        #pragma unroll
        for (int o=32;o>0;o>>=1) ss += __shfl_xor(ss, o);
        float scale = rsqrtf(ss/(float)D_INNER + EPS);
        bf16 outv[16];
        #pragma unroll
        for (int e=0;e<16;e++) outv[e] = f2b(g[e] * scale * nw[d0+e]);
        *(uint4*)zrow     = *(uint4*)&outv[0];
        *(uint4*)(zrow+8) = *(uint4*)&outv[8];
    }
}

// ---------------- hb += layernorm(tmp)*g + b (wave-per-token, no LDS) ----------------
__global__ __launch_bounds__(256) void k_resln(bf16* __restrict__ hb,
        const bf16* __restrict__ tmp,
        const float* __restrict__ g, const float* __restrict__ bb) {
    const int w = threadIdx.x >> 6, lane = threadIdx.x & 63;
    const size_t tok = (size_t)blockIdx.x*4 + w;
    const int d = lane*8;
    const size_t base = tok*D_MODEL + d;
    uint4 u4 = *(const uint4*)(tmp + base);
    const unsigned* uu = (const unsigned*)&u4;
    float v[8];
    #pragma unroll
    for (int e=0;e<4;e++) { v[2*e]=bflo(uu[e]); v[2*e+1]=bfhi(uu[e]); }
    float s=0.f, q=0.f;
    #pragma unroll
    for (int e=0;e<8;e++){ s += v[e]; q += v[e]*v[e]; }
    #pragma unroll
    for (int o=32;o>0;o>>=1){ s += __shfl_xor(s,o); q += __shfl_xor(q,o); }
    float mu  = s/(float)D_MODEL;
    float var = q/(float)D_MODEL - mu*mu;
    float inv = rsqrtf(var + EPS);
    uint4 h4 = *(const uint4*)(hb + base);
    const unsigned* hu = (const unsigned*)&h4;
    float4 g0 = *(const float4*)(g + d);
    float4 g1 = *(const float4*)(g + d + 4);
    float4 b0 = *(const float4*)(bb + d);
    float4 b1 = *(const float4*)(bb + d + 4);
    const float* gp0 = (const float*)&g0; const float* gp1 = (const float*)&g1;
    const float* bp0 = (const float*)&b0; const float* bp1 = (const float*)&b1;
    bf16 o8[8];
    #pragma unroll
    for (int e=0;e<4;e++) {
        float ge0 = (2*e < 4)   ? gp0[2*e]   : gp1[2*e-4];
        float ge1 = (2*e+1 < 4) ? gp0[2*e+1] : gp1[2*e+1-4];
        float be0 = (2*e < 4)   ? bp0[2*e]   : bp1[2*e-4];
        float be1 = (2*e+1 < 4) ? bp0[2*e+1] : bp1[2*e+1-4];
        float h0 = bflo(hu[e]) + (v[2*e]  -mu)*inv*ge0 + be0;
        float h1 = bfhi(hu[e]) + (v[2*e+1]-mu)*inv*ge1 + be1;
        o8[2*e] = f2b(h0); o8[2*e+1] = f2b(h1);
    }
    *(uint4*)(hb + base) = *(uint4*)&o8[0];
}

// ---------------- masked mean-pool over s (bf16 hb) ----------------
__global__ __launch_bounds__(256) void k_pool(const bf16* __restrict__ hb,
        float* __restrict__ pooled) {
    int b = blockIdx.x, t = threadIdx.x;
    __shared__ float ps[64][4];
    __shared__ float pm[64];
    __shared__ float cntS;
    {
        int s = t >> 2, qq = t & 3;
        const bf16* row = hb + ((size_t)b*SEQ + s)*D_MODEL + qq*128;
        float acc = 0;
        #pragma unroll
        for (int e=0;e<16;e++) {
            uint4 v = *(const uint4*)(row + e*8);
            const unsigned* vu = (const unsigned*)&v;
            #pragma unroll
            for (int k=0;k<4;k++) acc += bflo(vu[k]) + bfhi(vu[k]);
        }
        ps[s][qq] = acc;
    }
    __syncthreads();
    if (t < 64) pm[t] = (ps[t][0]+ps[t][1]+ps[t][2]+ps[t][3]) != 0.f ? 1.f : 0.f;
    __syncthreads();
    if (t == 0) { float c=0; for (int s2=0;s2<64;s2++) c+=pm[s2]; cntS = fmaxf(c,1.f); }
    __syncthreads();
    float cnt = cntS;
    #pragma unroll
    for (int rep=0;rep<2;rep++) {
        int d = t + rep*256;
        float acc = 0;
        for (int s2=0;s2<64;s2++)
            acc += b2f(hb[((size_t)b*SEQ+s2)*D_MODEL + d]) * pm[s2];
        pooled[(size_t)b*D_MODEL + d] = acc / cnt;
    }
}

// ---------------- fc1(relu) + fc2 ----------------
__global__ __launch_bounds__(128) void k_fc(const float* __restrict__ pooled,
        const float* __restrict__ w1, const float* __restrict__ b1,
        const float* __restrict__ w2, const float* __restrict__ b2,
        float* __restrict__ out) {
    int b = blockIdx.x, j = threadIdx.x;
    __shared__ float hid[FC_HID];
    const float* p  = pooled + (size_t)b*D_MODEL;
    const float* wr = w1 + (size_t)j*D_MODEL;
    float acc = b1[j];
    for (int d=0; d<D_MODEL; d+=4)
        acc += p[d]*wr[d] + p[d+1]*wr[d+1] + p[d+2]*wr[d+2] + p[d+3]*wr[d+3];
    hid[j] = fmaxf(acc, 0.f);
    __syncthreads();
    if (j < 2) {
        float o = b2[j];
        for (int k=0;k<FC_HID;k++) o += hid[k]*w2[j*FC_HID+k];
        out[b*2 + j] = o;
    }
}

extern "C" void kernel_launch(void* const* d_in, const int* in_sizes, int n_in,
                              void* d_out, int out_size, void* d_ws, size_t ws_size,
                              hipStream_t stream) {
    (void)in_sizes; (void)n_in; (void)out_size;
    const int*   x        = (const int*)  d_in[0];
    const float* emb      = (const float*)d_in[1];
    const float* pos      = (const float*)d_in[2];
    const float* in_proj  = (const float*)d_in[3];
    const float* conv_w   = (const float*)d_in[4];
    const float* conv_b   = (const float*)d_in[5];
    const float* dt_bias  = (const float*)d_in[6];
    const float* A_log    = (const float*)d_in[7];
    const float* D_skip   = (const float*)d_in[8];
    const float* norm_w   = (const float*)d_in[9];
    const float* out_proj = (const float*)d_in[10];
    const float* ln_g     = (const float*)d_in[11];
    const float* ln_b     = (const float*)d_in[12];
    const float* fc1_w    = (const float*)d_in[13];
    const float* fc1_b    = (const float*)d_in[14];
    const float* fc2_w    = (const float*)d_in[15];
    const float* fc2_b    = (const float*)d_in[16];
    float* out = (float*)d_out;

    // allow 150528 B dynamic LDS for fused SSD (idempotent, deterministic)
    const int SSD_LDS = 64*YPITCH*2 + 2*9216;     // 150528
    (void)hipFuncSetAttribute((const void*)k_ssd,
            hipFuncAttributeMaxDynamicSharedMemorySize, SSD_LDS);

    // ---- persistent region: bf16 residual stream + bf16 weights ----
    const size_t HB_B  = (size_t)NTOK * D_MODEL * 2;     // 32 MB bf16 residual
    const size_t WPI_B = (size_t)NPAD * D_MODEL * 2;     // per layer 2.49 MB
    const size_t WPO_B = (size_t)D_MODEL * D_INNER * 2;  // per layer 1 MB
    const size_t PBASE = HB_B + NLAYERS*(WPI_B + WPO_B); // ~39.3 MB

    // transients per token: z 2048 + xbcc 2560 + dt/cum 128 (ybuf eliminated: in-place)
    const size_t PER_TOK = 2048 + 2560 + 128;            // 4736 B
    int CB = BATCH;
    while (CB > 8 && PBASE + (size_t)CB*SEQ*PER_TOK > ws_size) CB >>= 1;
    const int CT = CB * SEQ;
    const int NC = BATCH / CB;

    char* ws = (char*)d_ws;
    bf16*  hb   = (bf16*) (ws);
    bf16*  wpi  = (bf16*) (ws + HB_B);                   // [NLAYERS][NPAD][512]
    bf16*  wpo  = (bf16*) (ws + HB_B + NLAYERS*WPI_B);   // [NLAYERS][512][1024]
    char*  tr   = ws + PBASE;
    bf16*  zbuf = (bf16*) (tr);                          // CT*1024 (z, then gated y in place)
    bf16*  xbcc = (bf16*) (tr + (size_t)CT*2048);        // CT*1280
    float* dt   = (float*)(tr + (size_t)CT*(2048+2560)); // [16][CT]
    float* cum  = dt + (size_t)CT*NHEADS;
    bf16*  tmp  = xbcc;                 // alias: xbcc dead after k_ssd
    float* pooled = (float*)tr;

    // weight conversion (both layers, once per launch)
    for (int l = 0; l < NLAYERS; l++) {
        int t8i = NPAD*D_MODEL/8;
        k_cvtw<<<(t8i+255)/256, 256, 0, stream>>>(in_proj + (size_t)l*D_IN_PROJ*D_MODEL,
                wpi + (size_t)l*NPAD*D_MODEL, D_IN_PROJ, D_MODEL, t8i);
        int t8o = D_MODEL*D_INNER/8;
        k_cvtw<<<(t8o+255)/256, 256, 0, stream>>>(out_proj + (size_t)l*D_MODEL*D_INNER,
                wpo + (size_t)l*D_MODEL*D_INNER, D_MODEL, D_INNER, t8o);
    }

    k_embed<<<(NTOK*128)/256, 256, 0, stream>>>(x, emb, pos, hb);

    const int NBX_I = NPAD/128;     // 19
    const int NBX_O = D_MODEL/128;  // 4

    for (int l = 0; l < NLAYERS; l++) {
        const bf16* wi = wpi + (size_t)l*NPAD*D_MODEL;
        const bf16* wo = wpo + (size_t)l*D_MODEL*D_INNER;
        for (int c = 0; c < NC; c++) {
            const int tok0 = c * CT;
            bf16* hbc = hb + (size_t)tok0 * D_MODEL;
            k_gemm128<1,512><<<(CT/128)*NBX_I, 256, 0, stream>>>(hbc, wi, zbuf,
                    xbcc, dt, cum,
                    conv_w + (size_t)l*CONV_DIM*D_CONV, conv_b + (size_t)l*CONV_DIM,
                    dt_bias + l*NHEADS, A_log + l*NHEADS,
                    NPAD, NBX_I, CT);
            k_ssd<<<CB, 256, SSD_LDS, stream>>>(xbcc, dt, cum, D_skip + l*NHEADS,
                    zbuf, norm_w + (size_t)l*D_INNER, CT);
            k_gemm128<0,1024><<<(CT/128)*NBX_O, 256, 0, stream>>>(zbuf, wo, tmp,
                    nullptr, nullptr, nullptr, nullptr, nullptr, nullptr, nullptr,
                    D_MODEL, NBX_O, CT);
            k_resln<<<CT/4, 256, 0, stream>>>(hbc, tmp, ln_g + l*D_MODEL, ln_b + l*D_MODEL);
        }
    }

    k_pool<<<BATCH, 256, 0, stream>>>(hb, pooled);
    k_fc<<<BATCH, FC_HID, 0, stream>>>(pooled, fc1_w, fc1_b, fc2_w, fc2_b, out);
}

// Round 17
// 583.667 us; speedup vs baseline: 1.3105x; 1.0092x over previous
//
#include <hip/hip_runtime.h>
#include <hip/hip_bf16.h>

// ---- problem constants ----
#define D_MODEL   512
#define D_STATE   128
#define D_CONV    4
#define HEADDIM   64
#define NLAYERS   2
#define D_INNER   1024
#define NHEADS    16
#define CONV_DIM  1280          // D_INNER + 2*D_STATE
#define D_IN_PROJ 2320          // 2*D_INNER + 2*D_STATE + NHEADS
#define NPAD      2432          // D_IN_PROJ padded to 128
#define SEQ       64
#define BATCH     512
#define NTOK      (BATCH*SEQ)   // 32768
#define FC_HID    128
#define EPS       1e-5f
#define YPITCH    1032          // D_INNER + 8 (LDS row pitch, 16B-aligned)

using bf16 = __hip_bfloat16;
typedef __bf16 bf16x8 __attribute__((ext_vector_type(8)));
typedef float  f32x4  __attribute__((ext_vector_type(4)));

__device__ __forceinline__ float b2f(bf16 v)  { return __bfloat162float(v); }
__device__ __forceinline__ bf16  f2b(float v) { return __float2bfloat16(v); }
__device__ __forceinline__ float bflo(unsigned u){ return __builtin_bit_cast(float, u << 16); }
__device__ __forceinline__ float bfhi(unsigned u){ return __builtin_bit_cast(float, u & 0xffff0000u); }

__device__ __forceinline__ void gl_lds16(const void* g, void* l) {
    __builtin_amdgcn_global_load_lds((const __attribute__((address_space(1))) void*)g,
                                     (__attribute__((address_space(3))) void*)l, 16, 0, 0);
}

// ---------------- embedding: hb = bf16(emb[x]+pos)  (bf16 residual stream) ----------------
__global__ __launch_bounds__(256) void k_embed(const int* __restrict__ x,
        const float* __restrict__ emb, const float* __restrict__ pos,
        bf16* __restrict__ hb) {
    int idx = blockIdx.x*256 + threadIdx.x;     // NTOK*128
    int d   = (idx & 127) * 4;
    int tok = idx >> 7;
    int s   = tok & (SEQ-1);
    int v   = x[tok];
    float4 e4 = *(const float4*)(emb + (size_t)v*D_MODEL + d);
    float4 p4 = *(const float4*)(pos + (size_t)s*D_MODEL + d);
    bf16 o[4] = { f2b(e4.x+p4.x), f2b(e4.y+p4.y), f2b(e4.z+p4.z), f2b(e4.w+p4.w) };
    *(uint2*)(hb + (size_t)tok*D_MODEL + d) = *(uint2*)&o[0];
}

// ---------------- weight convert f32 -> bf16, zero-padded rows ----------------
__global__ __launch_bounds__(256) void k_cvtw(const float* __restrict__ src,
        bf16* __restrict__ dst, int R, int Kc, int total8) {
    int idx = blockIdx.x*256 + threadIdx.x;
    if (idx >= total8) return;
    int e0 = idx*8;
    int r = e0 / Kc, c = e0 % Kc;
    bf16 tb[8];
    if (r < R) {
        float4 f0 = *(const float4*)(src + (size_t)r*Kc + c);
        float4 f1 = *(const float4*)(src + (size_t)r*Kc + c + 4);
        tb[0]=f2b(f0.x); tb[1]=f2b(f0.y); tb[2]=f2b(f0.z); tb[3]=f2b(f0.w);
        tb[4]=f2b(f1.x); tb[5]=f2b(f1.y); tb[6]=f2b(f1.z); tb[7]=f2b(f1.w);
    } else {
        #pragma unroll
        for (int e=0;e<8;e++) tb[e] = f2b(0.f);
    }
    *(uint4*)(dst + (size_t)r*Kc + c) = *(uint4*)&tb[0];
}

// ---------------- GEMM 128x128 (round-7/14 best config: 64KB dbuf, issue-early, setprio) ----------------
// FUSE=1: in_proj epilogue (z / conv+silu / dt-scan). FUSE=0: plain store.
template<int FUSE, int KDIM>
__global__ __launch_bounds__(256) void k_gemm128(const bf16* __restrict__ A,
        const bf16* __restrict__ B, bf16* __restrict__ C,
        bf16* __restrict__ xbcc, float* __restrict__ dt, float* __restrict__ cum,
        const float* __restrict__ cw, const float* __restrict__ cb,
        const float* __restrict__ dt_bias, const float* __restrict__ A_log,
        int Nout, int nbx, int ctok)
{
    constexpr int NT = KDIM / 64;
    __shared__ __align__(16) char lds[65536];      // 2 buffers x (A 16K + B 16K)
    bf16* Cs = (bf16*)lds;                         // epilogue repack alias [128][136]

    // bijective XCD swizzle (m204)
    const int nwg = gridDim.x;
    const int q = nwg >> 3, r = nwg & 7;
    const int xcd = blockIdx.x & 7, loc = blockIdx.x >> 3;
    const int wg = ((xcd < r) ? xcd*(q+1) : r*(q+1) + (xcd-r)*q) + loc;
    const int m0 = (wg / nbx) * 128;
    const int n0 = (wg % nbx) * 128;

    const int t = threadIdx.x;
    const int wid = t >> 6, lane = t & 63;
    const int lr = lane & 15, lg = lane >> 4;
    const int wm = (wid >> 1)*64, wn = (wid & 1)*64;
    const int srow = wid*32;
    const int sr   = lane >> 3;                    // row-in-chunk 0..7
    const int scol = ((lane & 7) ^ sr) * 8;        // pre-swizzled source slot

    const bf16* Abase = A + (size_t)(m0 + srow + sr)*KDIM + scol;
    const bf16* Bbase = B + (size_t)(n0 + srow + sr)*KDIM + scol;

    f32x4 acc[4][4] = {};
    char* bc = lds;             // compute buffer
    char* bn = lds + 32768;     // staging buffer

    auto STAGE = [&](char* buf, int kk) {
        #pragma unroll
        for (int c = 0; c < 4; c++) {
            gl_lds16(Abase + (size_t)(c*8)*KDIM + kk, buf + (srow + c*8)*128);
            gl_lds16(Bbase + (size_t)(c*8)*KDIM + kk, buf + 16384 + (srow + c*8)*128);
        }
    };

    STAGE(bc, 0);
    asm volatile("s_waitcnt vmcnt(0)" ::: "memory");
    __builtin_amdgcn_s_barrier();

    #pragma unroll
    for (int kt = 0; kt < NT; kt++) {
        if (kt + 1 < NT) STAGE(bn, (kt+1)*64);     // issue-early: lands under MFMA
        #pragma unroll
        for (int ks = 0; ks < 64; ks += 32) {
            bf16x8 a[4], b[4];
            #pragma unroll
            for (int mi=0;mi<4;mi++) {
                int ra = wm + mi*16 + lr;
                a[mi] = *(const bf16x8*)(bc + ra*128 + ((((ks>>3)+lg) ^ (ra&7))<<4));
            }
            #pragma unroll
            for (int ni=0;ni<4;ni++) {
                int rb = wn + ni*16 + lr;
                b[ni] = *(const bf16x8*)(bc + 16384 + rb*128 + ((((ks>>3)+lg) ^ (rb&7))<<4));
            }
            __builtin_amdgcn_s_setprio(1);
            #pragma unroll
            for (int mi=0;mi<4;mi++)
                #pragma unroll
                for (int ni=0;ni<4;ni++)
                    acc[mi][ni] = __builtin_amdgcn_mfma_f32_16x16x32_bf16(a[mi], b[ni], acc[mi][ni], 0,0,0);
            __builtin_amdgcn_s_setprio(0);
        }
        asm volatile("s_waitcnt vmcnt(0)" ::: "memory");   // this iter's stage: hidden
        __builtin_amdgcn_s_barrier();
        char* tb2 = bc; bc = bn; bn = tb2;
    }
    __builtin_amdgcn_sched_barrier(0);

    // repack C tile into LDS (bank-safe: stride 136) — staging buffers dead
    #pragma unroll
    for (int mi=0;mi<4;mi++)
        #pragma unroll
        for (int ni=0;ni<4;ni++)
            #pragma unroll
            for (int rr=0;rr<4;rr++)
                Cs[(wm+mi*16+lg*4+rr)*136 + wn+ni*16+lr] = f2b(acc[mi][ni][rr]);
    __syncthreads();

    const int rsub = t >> 4;            // 0..15
    const int c8   = (t & 15) * 8;      // constant per thread across store loop

    if (FUSE == 0 || n0 < 1024) {
        const int strd = (FUSE == 0) ? Nout : 1024;
        #pragma unroll
        for (int it = 0; it < 8; it++) {
            int row = it*16 + rsub;
            *(uint4*)(C + (size_t)(m0+row)*strd + n0 + c8) = *(const uint4*)&Cs[row*136 + c8];
        }
    } else if (n0 < 2304) {
        // depthwise causal conv + silu -> xbcc
        const int cbase = n0 - 1024 + c8;
        float4 wreg[8]; float bias[8];
        #pragma unroll
        for (int e=0;e<8;e++) wreg[e] = *(const float4*)(cw + (size_t)(cbase+e)*4);
        {
            float4 b0 = *(const float4*)(cb + cbase);
            float4 b1 = *(const float4*)(cb + cbase + 4);
            bias[0]=b0.x; bias[1]=b0.y; bias[2]=b0.z; bias[3]=b0.w;
            bias[4]=b1.x; bias[5]=b1.y; bias[6]=b1.z; bias[7]=b1.w;
        }
        #pragma unroll
        for (int it = 0; it < 8; it++) {
            int row = it*16 + rsub;
            int sl  = row & (SEQ-1);
            float m3 = (sl >= 3) ? 1.f : 0.f;
            float m2 = (sl >= 2) ? 1.f : 0.f;
            float m1 = (sl >= 1) ? 1.f : 0.f;
            const bf16* sm3 = &Cs[(row-3)*136 + c8];
            const bf16* sm2 = &Cs[(row-2)*136 + c8];
            const bf16* sm1 = &Cs[(row-1)*136 + c8];
            const bf16* sm0 = &Cs[(row  )*136 + c8];
            float a[8];
            #pragma unroll
            for (int e=0;e<8;e++) {
                a[e] = bias[e]
                     + m3 * b2f(sm3[e]) * wreg[e].x
                     + m2 * b2f(sm2[e]) * wreg[e].y
                     + m1 * b2f(sm1[e]) * wreg[e].z
                     +      b2f(sm0[e]) * wreg[e].w;
            }
            bf16 outv[8];
            #pragma unroll
            for (int e=0;e<8;e++) outv[e] = f2b(a[e] / (1.f + __expf(-a[e])));
            *(uint4*)(xbcc + (size_t)(m0+row)*CONV_DIM + cbase) = *(uint4*)&outv[0];
        }
    } else {
        // dt tile: softplus + cumsum scan over each sequence, write dt/cum f32
        for (int p = wid; p < 32; p += 4) {       // (seq-in-tile, head)
            int sq = p >> 4, head = p & 15;
            float raw = b2f(Cs[(sq*64 + lane)*136 + head]) + dt_bias[head];
            float dval = (raw > 20.f) ? raw : log1pf(__expf(raw));
            float Ah = -__expf(A_log[head]);
            float cc = dval * Ah;
            #pragma unroll
            for (int o=1;o<64;o<<=1) { float v = __shfl_up(cc, o); if (lane >= o) cc += v; }
            int tok = m0 + sq*64 + lane;
            dt [(size_t)head*ctok + tok] = dval;
            cum[(size_t)head*ctok + tok] = cc;
        }
    }
}

// ---------------- SSD core v4: token-split (2 blocks/batch), fused gate/RMS, in-place ----------------
// Block handles 32 token rows (half = bid&1) x all 16 heads. LDS 79872 B -> 2 blocks/CU.
// Waves 0/1 compute the 32 score rows (16 each, registers); all 4 waves do the y-MFMA
// (wave = 16 rows x 32 cols). Math per element identical to v3c.
__global__ __launch_bounds__(256) void k_ssd(const bf16* __restrict__ xbcc,
        const float* __restrict__ dt, const float* __restrict__ cum,
        const float* __restrict__ Dskip, bf16* zio,
        const float* __restrict__ nw, int ctok) {
    extern __shared__ __align__(16) char sm[];
    bf16* yb  = (bf16*)sm;                                   // [32][YPITCH] 66048 B
    bf16* Wb  = (bf16*)(sm + 32*YPITCH*2);                   // [32][72] 4608 B
    bf16* xsT = (bf16*)(sm + 32*YPITCH*2 + 4608);            // [64][72] 9216 B
    const int bid = blockIdx.x;
    const int b   = bid >> 1;
    const int r0  = (bid & 1) * 32;                           // token-row base in batch
    const int t = threadIdx.x;
    const size_t tokbase = (size_t)b*SEQ;
    const int lane = t & 63, lr = lane & 15, lg = lane >> 4;
    const int w = t >> 6;

    // scores rows [r0 + (w&1)*16, +16) in registers (waves 0/1 only)
    f32x4 sacc[4] = {};
    const int irel0 = (w & 1) * 16;                           // block-relative row base
    if (w < 2) {
        const int i0 = r0 + irel0;
        const bf16* Cbase = xbcc + tokbase*CONV_DIM + D_INNER + D_STATE;
        const bf16* Bbase = xbcc + tokbase*CONV_DIM + D_INNER;
        #pragma unroll
        for (int ks = 0; ks < D_STATE; ks += 32) {
            bf16x8 af = *(const bf16x8*)(Cbase + (size_t)(i0+lr)*CONV_DIM + ks + lg*8);
            #pragma unroll
            for (int jt = 0; jt < 4; jt++) {
                bf16x8 bfr = *(const bf16x8*)(Bbase + (size_t)(jt*16+lr)*CONV_DIM + ks + lg*8);
                sacc[jt] = __builtin_amdgcn_mfma_f32_16x16x32_bf16(af, bfr, sacc[jt], 0,0,0);
            }
        }
    }

    for (int hh = 0; hh < NHEADS; hh++) {
        const size_t cbase = (size_t)hh*ctok + tokbase;
        __syncthreads();   // prev head's MFMA readers done -> Wb/xsT reusable

        // stage xsT (transpose xs, full 64 tokens)
        #pragma unroll
        for (int cc = 0; cc < 2; cc++) {
            int ch = cc*256 + t;
            int rr = ch >> 3, c8 = (ch & 7)*8;
            uint4 v = *(const uint4*)(xbcc + (tokbase + rr)*CONV_DIM + hh*HEADDIM + c8);
            const bf16* pv = (const bf16*)&v;
            #pragma unroll
            for (int e=0;e<8;e++) xsT[(c8+e)*72 + rr] = pv[e];
        }
        // build Wb rows [irel0, +16) from register scores (waves 0/1)
        if (w < 2) {
            float cum_i[4], cum_j[4], dt_j[4];
            #pragma unroll
            for (int rr=0;rr<4;rr++) cum_i[rr] = cum[cbase + r0 + irel0 + lg*4 + rr];
            #pragma unroll
            for (int jt=0;jt<4;jt++) { int j = jt*16+lr; cum_j[jt]=cum[cbase+j]; dt_j[jt]=dt[cbase+j]; }
            #pragma unroll
            for (int jt=0;jt<4;jt++)
                #pragma unroll
                for (int rr=0;rr<4;rr++) {
                    int irel = irel0 + lg*4 + rr, j = jt*16 + lr;
                    float wv = (j <= r0 + irel)
                             ? sacc[jt][rr] * __expf(cum_i[rr]-cum_j[jt]) * dt_j[jt] : 0.f;
                    Wb[irel*72 + j] = f2b(wv);
                }
        }
        __syncthreads();

        // y[32x64] = Wb @ xsT^T + Dskip*xs ; wave = rows (w&1)*16, cols (w>>1)*32
        {
            float dsk = Dskip[hh];
            const int ro = (w & 1) * 16, co = (w >> 1) * 32;
            f32x4 yacc[2] = {};
            #pragma unroll
            for (int ks = 0; ks < 64; ks += 32) {
                bf16x8 a = *(const bf16x8*)&Wb[(ro + lr)*72 + ks + lg*8];
                #pragma unroll
                for (int n=0; n<2; n++) {
                    bf16x8 bb = *(const bf16x8*)&xsT[(co + n*16 + lr)*72 + ks + lg*8];
                    yacc[n] = __builtin_amdgcn_mfma_f32_16x16x32_bf16(a, bb, yacc[n], 0,0,0);
                }
            }
            #pragma unroll
            for (int n=0; n<2; n++)
                #pragma unroll
                for (int rr=0; rr<4; rr++) {
                    int row = ro + lg*4 + rr;             // block-relative token
                    int col = co + n*16 + lr;
                    yb[row*YPITCH + hh*HEADDIM + col] =
                        f2b(yacc[n][rr] + dsk * b2f(xsT[col*72 + (r0 + row)]));
                }
        }
    }
    __syncthreads();   // yb complete

    // ---- fused gate + RMS-norm, wave-per-token, in-place into zio ----
    for (int pass = 0; pass < 8; pass++) {
        const int trel = pass*4 + w;                  // 0..31
        const int d0  = lane*16;
        bf16* zrow        = zio + (tokbase + r0 + trel)*D_INNER + d0;
        const bf16* ybrow = yb + trel*YPITCH + d0;
        uint4 yv0 = *(const uint4*)(ybrow);
        uint4 yv1 = *(const uint4*)(ybrow + 8);
        uint4 zv0 = *(const uint4*)(zrow);
        uint4 zv1 = *(const uint4*)(zrow + 8);
        const unsigned* yu0 = (const unsigned*)&yv0;
        const unsigned* yu1 = (const unsigned*)&yv1;
        const unsigned* zu0 = (const unsigned*)&zv0;
        const unsigned* zu1 = (const unsigned*)&zv1;
        float g[16]; float ss = 0.f;
        #pragma unroll
        for (int e=0;e<4;e++) {
            float y0 = bflo(yu0[e]), y1 = bfhi(yu0[e]);
            float z0 = bflo(zu0[e]), z1 = bfhi(zu0[e]);
            float g0 = y0 * z0 / (1.f + __expf(-z0));
            float g1 = y1 * z1 / (1.f + __expf(-z1));
            g[2*e] = g0; g[2*e+1] = g1;
            ss += g0*g0 + g1*g1;
            float y2 = bflo(yu1[e]), y3 = bfhi(yu1[e]);
            float z2 = bflo(zu1[e]), z3 = bfhi(zu1[e]);
            float g2 = y2 * z2 / (1.f + __expf(-z2));
            float g3 = y3 * z3 / (1.f + __expf(-z3));
            g[8+2*e] = g2; g[8+2*e+1] = g3;
            ss += g2*g2 + g3*g3;
        }
        #pragma unroll
        for (int o=32;o>0;o>>=1) ss += __shfl_xor(ss, o);
        float scale = rsqrtf(ss/(float)D_INNER + EPS);
        bf16 outv[16];
        #pragma unroll
        for (int e=0;e<16;e++) outv[e] = f2b(g[e] * scale * nw[d0+e]);
        *(uint4*)zrow     = *(uint4*)&outv[0];
        *(uint4*)(zrow+8) = *(uint4*)&outv[8];
    }
}

// ---------------- hb += layernorm(tmp)*g + b (wave-per-token, no LDS) ----------------
__global__ __launch_bounds__(256) void k_resln(bf16* __restrict__ hb,
        const bf16* __restrict__ tmp,
        const float* __restrict__ g, const float* __restrict__ bb) {
    const int w = threadIdx.x >> 6, lane = threadIdx.x & 63;
    const size_t tok = (size_t)blockIdx.x*4 + w;
    const int d = lane*8;
    const size_t base = tok*D_MODEL + d;
    uint4 u4 = *(const uint4*)(tmp + base);
    const unsigned* uu = (const unsigned*)&u4;
    float v[8];
    #pragma unroll
    for (int e=0;e<4;e++) { v[2*e]=bflo(uu[e]); v[2*e+1]=bfhi(uu[e]); }
    float s=0.f, q=0.f;
    #pragma unroll
    for (int e=0;e<8;e++){ s += v[e]; q += v[e]*v[e]; }
    #pragma unroll
    for (int o=32;o>0;o>>=1){ s += __shfl_xor(s,o); q += __shfl_xor(q,o); }
    float mu  = s/(float)D_MODEL;
    float var = q/(float)D_MODEL - mu*mu;
    float inv = rsqrtf(var + EPS);
    uint4 h4 = *(const uint4*)(hb + base);
    const unsigned* hu = (const unsigned*)&h4;
    float4 g0 = *(const float4*)(g + d);
    float4 g1 = *(const float4*)(g + d + 4);
    float4 b0 = *(const float4*)(bb + d);
    float4 b1 = *(const float4*)(bb + d + 4);
    const float* gp0 = (const float*)&g0; const float* gp1 = (const float*)&g1;
    const float* bp0 = (const float*)&b0; const float* bp1 = (const float*)&b1;
    bf16 o8[8];
    #pragma unroll
    for (int e=0;e<4;e++) {
        float ge0 = (2*e < 4)   ? gp0[2*e]   : gp1[2*e-4];
        float ge1 = (2*e+1 < 4) ? gp0[2*e+1] : gp1[2*e+1-4];
        float be0 = (2*e < 4)   ? bp0[2*e]   : bp1[2*e-4];
        float be1 = (2*e+1 < 4) ? bp0[2*e+1] : bp1[2*e+1-4];
        float h0 = bflo(hu[e]) + (v[2*e]  -mu)*inv*ge0 + be0;
        float h1 = bfhi(hu[e]) + (v[2*e+1]-mu)*inv*ge1 + be1;
        o8[2*e] = f2b(h0); o8[2*e+1] = f2b(h1);
    }
    *(uint4*)(hb + base) = *(uint4*)&o8[0];
}

// ---------------- masked mean-pool over s (bf16 hb) ----------------
__global__ __launch_bounds__(256) void k_pool(const bf16* __restrict__ hb,
        float* __restrict__ pooled) {
    int b = blockIdx.x, t = threadIdx.x;
    __shared__ float ps[64][4];
    __shared__ float pm[64];
    __shared__ float cntS;
    {
        int s = t >> 2, qq = t & 3;
        const bf16* row = hb + ((size_t)b*SEQ + s)*D_MODEL + qq*128;
        float acc = 0;
        #pragma unroll
        for (int e=0;e<16;e++) {
            uint4 v = *(const uint4*)(row + e*8);
            const unsigned* vu = (const unsigned*)&v;
            #pragma unroll
            for (int k=0;k<4;k++) acc += bflo(vu[k]) + bfhi(vu[k]);
        }
        ps[s][qq] = acc;
    }
    __syncthreads();
    if (t < 64) pm[t] = (ps[t][0]+ps[t][1]+ps[t][2]+ps[t][3]) != 0.f ? 1.f : 0.f;
    __syncthreads();
    if (t == 0) { float c=0; for (int s2=0;s2<64;s2++) c+=pm[s2]; cntS = fmaxf(c,1.f); }
    __syncthreads();
    float cnt = cntS;
    #pragma unroll
    for (int rep=0;rep<2;rep++) {
        int d = t + rep*256;
        float acc = 0;
        for (int s2=0;s2<64;s2++)
            acc += b2f(hb[((size_t)b*SEQ+s2)*D_MODEL + d]) * pm[s2];
        pooled[(size_t)b*D_MODEL + d] = acc / cnt;
    }
}

// ---------------- fc1(relu) + fc2 ----------------
__global__ __launch_bounds__(128) void k_fc(const float* __restrict__ pooled,
        const float* __restrict__ w1, const float* __restrict__ b1,
        const float* __restrict__ w2, const float* __restrict__ b2,
        float* __restrict__ out) {
    int b = blockIdx.x, j = threadIdx.x;
    __shared__ float hid[FC_HID];
    const float* p  = pooled + (size_t)b*D_MODEL;
    const float* wr = w1 + (size_t)j*D_MODEL;
    float acc = b1[j];
    for (int d=0; d<D_MODEL; d+=4)
        acc += p[d]*wr[d] + p[d+1]*wr[d+1] + p[d+2]*wr[d+2] + p[d+3]*wr[d+3];
    hid[j] = fmaxf(acc, 0.f);
    __syncthreads();
    if (j < 2) {
        float o = b2[j];
        for (int k=0;k<FC_HID;k++) o += hid[k]*w2[j*FC_HID+k];
        out[b*2 + j] = o;
    }
}

extern "C" void kernel_launch(void* const* d_in, const int* in_sizes, int n_in,
                              void* d_out, int out_size, void* d_ws, size_t ws_size,
                              hipStream_t stream) {
    (void)in_sizes; (void)n_in; (void)out_size;
    const int*   x        = (const int*)  d_in[0];
    const float* emb      = (const float*)d_in[1];
    const float* pos      = (const float*)d_in[2];
    const float* in_proj  = (const float*)d_in[3];
    const float* conv_w   = (const float*)d_in[4];
    const float* conv_b   = (const float*)d_in[5];
    const float* dt_bias  = (const float*)d_in[6];
    const float* A_log    = (const float*)d_in[7];
    const float* D_skip   = (const float*)d_in[8];
    const float* norm_w   = (const float*)d_in[9];
    const float* out_proj = (const float*)d_in[10];
    const float* ln_g     = (const float*)d_in[11];
    const float* ln_b     = (const float*)d_in[12];
    const float* fc1_w    = (const float*)d_in[13];
    const float* fc1_b    = (const float*)d_in[14];
    const float* fc2_w    = (const float*)d_in[15];
    const float* fc2_b    = (const float*)d_in[16];
    float* out = (float*)d_out;

    // allow 79872 B dynamic LDS for token-split SSD (2 blocks/CU)
    const int SSD_LDS = 32*YPITCH*2 + 4608 + 9216;   // 79872
    (void)hipFuncSetAttribute((const void*)k_ssd,
            hipFuncAttributeMaxDynamicSharedMemorySize, SSD_LDS);

    // ---- persistent region: bf16 residual stream + bf16 weights ----
    const size_t HB_B  = (size_t)NTOK * D_MODEL * 2;     // 32 MB bf16 residual
    const size_t WPI_B = (size_t)NPAD * D_MODEL * 2;     // per layer 2.49 MB
    const size_t WPO_B = (size_t)D_MODEL * D_INNER * 2;  // per layer 1 MB
    const size_t PBASE = HB_B + NLAYERS*(WPI_B + WPO_B); // ~39.3 MB

    // transients per token: z 2048 + xbcc 2560 + dt/cum 128 (ybuf eliminated: in-place)
    const size_t PER_TOK = 2048 + 2560 + 128;            // 4736 B
    int CB = BATCH;
    while (CB > 8 && PBASE + (size_t)CB*SEQ*PER_TOK > ws_size) CB >>= 1;
    const int CT = CB * SEQ;
    const int NC = BATCH / CB;

    char* ws = (char*)d_ws;
    bf16*  hb   = (bf16*) (ws);
    bf16*  wpi  = (bf16*) (ws + HB_B);                   // [NLAYERS][NPAD][512]
    bf16*  wpo  = (bf16*) (ws + HB_B + NLAYERS*WPI_B);   // [NLAYERS][512][1024]
    char*  tr   = ws + PBASE;
    bf16*  zbuf = (bf16*) (tr);                          // CT*1024 (z, then gated y in place)
    bf16*  xbcc = (bf16*) (tr + (size_t)CT*2048);        // CT*1280
    float* dt   = (float*)(tr + (size_t)CT*(2048+2560)); // [16][CT]
    float* cum  = dt + (size_t)CT*NHEADS;
    bf16*  tmp  = xbcc;                 // alias: xbcc dead after k_ssd
    float* pooled = (float*)tr;

    // weight conversion (both layers, once per launch)
    for (int l = 0; l < NLAYERS; l++) {
        int t8i = NPAD*D_MODEL/8;
        k_cvtw<<<(t8i+255)/256, 256, 0, stream>>>(in_proj + (size_t)l*D_IN_PROJ*D_MODEL,
                wpi + (size_t)l*NPAD*D_MODEL, D_IN_PROJ, D_MODEL, t8i);
        int t8o = D_MODEL*D_INNER/8;
        k_cvtw<<<(t8o+255)/256, 256, 0, stream>>>(out_proj + (size_t)l*D_MODEL*D_INNER,
                wpo + (size_t)l*D_MODEL*D_INNER, D_MODEL, D_INNER, t8o);
    }

    k_embed<<<(NTOK*128)/256, 256, 0, stream>>>(x, emb, pos, hb);

    const int NBX_I = NPAD/128;     // 19
    const int NBX_O = D_MODEL/128;  // 4

    for (int l = 0; l < NLAYERS; l++) {
        const bf16* wi = wpi + (size_t)l*NPAD*D_MODEL;
        const bf16* wo = wpo + (size_t)l*D_MODEL*D_INNER;
        for (int c = 0; c < NC; c++) {
            const int tok0 = c * CT;
            bf16* hbc = hb + (size_t)tok0 * D_MODEL;
            k_gemm128<1,512><<<(CT/128)*NBX_I, 256, 0, stream>>>(hbc, wi, zbuf,
                    xbcc, dt, cum,
                    conv_w + (size_t)l*CONV_DIM*D_CONV, conv_b + (size_t)l*CONV_DIM,
                    dt_bias + l*NHEADS, A_log + l*NHEADS,
                    NPAD, NBX_I, CT);
            k_ssd<<<CB*2, 256, SSD_LDS, stream>>>(xbcc, dt, cum, D_skip + l*NHEADS,
                    zbuf, norm_w + (size_t)l*D_INNER, CT);
            k_gemm128<0,1024><<<(CT/128)*NBX_O, 256, 0, stream>>>(zbuf, wo, tmp,
                    nullptr, nullptr, nullptr, nullptr, nullptr, nullptr, nullptr,
                    D_MODEL, NBX_O, CT);
            k_resln<<<CT/4, 256, 0, stream>>>(hbc, tmp, ln_g + l*D_MODEL, ln_b + l*D_MODEL);
        }
    }

    k_pool<<<BATCH, 256, 0, stream>>>(hb, pooled);
    k_fc<<<BATCH, FC_HID, 0, stream>>>(pooled, fc1_w, fc1_b, fc2_w, fc2_b, out);
}

// Round 18
// 573.171 us; speedup vs baseline: 1.3345x; 1.0183x over previous
//
#include <hip/hip_runtime.h>
#include <hip/hip_bf16.h>

// ---- problem constants ----
#define D_MODEL   512
#define D_STATE   128
#define D_CONV    4
#define HEADDIM   64
#define NLAYERS   2
#define D_INNER   1024
#define NHEADS    16
#define CONV_DIM  1280          // D_INNER + 2*D_STATE
#define D_IN_PROJ 2320          // 2*D_INNER + 2*D_STATE + NHEADS
#define NPAD      2432          // D_IN_PROJ padded to 128
#define SEQ       64
#define BATCH     512
#define NTOK      (BATCH*SEQ)   // 32768
#define FC_HID    128
#define EPS       1e-5f
#define YPITCH    1032          // D_INNER + 8 (LDS row pitch, 16B-aligned)

using bf16 = __hip_bfloat16;
typedef __bf16 bf16x8 __attribute__((ext_vector_type(8)));
typedef float  f32x4  __attribute__((ext_vector_type(4)));

__device__ __forceinline__ float b2f(bf16 v)  { return __bfloat162float(v); }
__device__ __forceinline__ bf16  f2b(float v) { return __float2bfloat16(v); }
__device__ __forceinline__ float bflo(unsigned u){ return __builtin_bit_cast(float, u << 16); }
__device__ __forceinline__ float bfhi(unsigned u){ return __builtin_bit_cast(float, u & 0xffff0000u); }

__device__ __forceinline__ void gl_lds16(const void* g, void* l) {
    __builtin_amdgcn_global_load_lds((const __attribute__((address_space(1))) void*)g,
                                     (__attribute__((address_space(3))) void*)l, 16, 0, 0);
}

// ---------------- embedding: hb = bf16(emb[x]+pos)  (bf16 residual stream) ----------------
__global__ __launch_bounds__(256) void k_embed(const int* __restrict__ x,
        const float* __restrict__ emb, const float* __restrict__ pos,
        bf16* __restrict__ hb) {
    int idx = blockIdx.x*256 + threadIdx.x;     // NTOK*128
    int d   = (idx & 127) * 4;
    int tok = idx >> 7;
    int s   = tok & (SEQ-1);
    int v   = x[tok];
    float4 e4 = *(const float4*)(emb + (size_t)v*D_MODEL + d);
    float4 p4 = *(const float4*)(pos + (size_t)s*D_MODEL + d);
    bf16 o[4] = { f2b(e4.x+p4.x), f2b(e4.y+p4.y), f2b(e4.z+p4.z), f2b(e4.w+p4.w) };
    *(uint2*)(hb + (size_t)tok*D_MODEL + d) = *(uint2*)&o[0];
}

// ---------------- weight convert f32 -> bf16, zero-padded rows ----------------
__global__ __launch_bounds__(256) void k_cvtw(const float* __restrict__ src,
        bf16* __restrict__ dst, int R, int Kc, int total8) {
    int idx = blockIdx.x*256 + threadIdx.x;
    if (idx >= total8) return;
    int e0 = idx*8;
    int r = e0 / Kc, c = e0 % Kc;
    bf16 tb[8];
    if (r < R) {
        float4 f0 = *(const float4*)(src + (size_t)r*Kc + c);
        float4 f1 = *(const float4*)(src + (size_t)r*Kc + c + 4);
        tb[0]=f2b(f0.x); tb[1]=f2b(f0.y); tb[2]=f2b(f0.z); tb[3]=f2b(f0.w);
        tb[4]=f2b(f1.x); tb[5]=f2b(f1.y); tb[6]=f2b(f1.z); tb[7]=f2b(f1.w);
    } else {
        #pragma unroll
        for (int e=0;e<8;e++) tb[e] = f2b(0.f);
    }
    *(uint4*)(dst + (size_t)r*Kc + c) = *(uint4*)&tb[0];
}

// ---------------- GEMM 128x128 (round-7/14 best config: 64KB dbuf, issue-early, setprio) ----------------
// FUSE=1: in_proj epilogue (z / conv+silu / dt-scan). FUSE=0: plain store.
template<int FUSE, int KDIM>
__global__ __launch_bounds__(256) void k_gemm128(const bf16* __restrict__ A,
        const bf16* __restrict__ B, bf16* __restrict__ C,
        bf16* __restrict__ xbcc, float* __restrict__ dt, float* __restrict__ cum,
        const float* __restrict__ cw, const float* __restrict__ cb,
        const float* __restrict__ dt_bias, const float* __restrict__ A_log,
        int Nout, int nbx, int ctok)
{
    constexpr int NT = KDIM / 64;
    __shared__ __align__(16) char lds[65536];      // 2 buffers x (A 16K + B 16K)
    bf16* Cs = (bf16*)lds;                         // epilogue repack alias [128][136]

    // bijective XCD swizzle (m204)
    const int nwg = gridDim.x;
    const int q = nwg >> 3, r = nwg & 7;
    const int xcd = blockIdx.x & 7, loc = blockIdx.x >> 3;
    const int wg = ((xcd < r) ? xcd*(q+1) : r*(q+1) + (xcd-r)*q) + loc;
    const int m0 = (wg / nbx) * 128;
    const int n0 = (wg % nbx) * 128;

    const int t = threadIdx.x;
    const int wid = t >> 6, lane = t & 63;
    const int lr = lane & 15, lg = lane >> 4;
    const int wm = (wid >> 1)*64, wn = (wid & 1)*64;
    const int srow = wid*32;
    const int sr   = lane >> 3;                    // row-in-chunk 0..7
    const int scol = ((lane & 7) ^ sr) * 8;        // pre-swizzled source slot

    const bf16* Abase = A + (size_t)(m0 + srow + sr)*KDIM + scol;
    const bf16* Bbase = B + (size_t)(n0 + srow + sr)*KDIM + scol;

    f32x4 acc[4][4] = {};
    char* bc = lds;             // compute buffer
    char* bn = lds + 32768;     // staging buffer

    auto STAGE = [&](char* buf, int kk) {
        #pragma unroll
        for (int c = 0; c < 4; c++) {
            gl_lds16(Abase + (size_t)(c*8)*KDIM + kk, buf + (srow + c*8)*128);
            gl_lds16(Bbase + (size_t)(c*8)*KDIM + kk, buf + 16384 + (srow + c*8)*128);
        }
    };

    STAGE(bc, 0);
    asm volatile("s_waitcnt vmcnt(0)" ::: "memory");
    __builtin_amdgcn_s_barrier();

    #pragma unroll
    for (int kt = 0; kt < NT; kt++) {
        if (kt + 1 < NT) STAGE(bn, (kt+1)*64);     // issue-early: lands under MFMA
        #pragma unroll
        for (int ks = 0; ks < 64; ks += 32) {
            bf16x8 a[4], b[4];
            #pragma unroll
            for (int mi=0;mi<4;mi++) {
                int ra = wm + mi*16 + lr;
                a[mi] = *(const bf16x8*)(bc + ra*128 + ((((ks>>3)+lg) ^ (ra&7))<<4));
            }
            #pragma unroll
            for (int ni=0;ni<4;ni++) {
                int rb = wn + ni*16 + lr;
                b[ni] = *(const bf16x8*)(bc + 16384 + rb*128 + ((((ks>>3)+lg) ^ (rb&7))<<4));
            }
            __builtin_amdgcn_s_setprio(1);
            #pragma unroll
            for (int mi=0;mi<4;mi++)
                #pragma unroll
                for (int ni=0;ni<4;ni++)
                    acc[mi][ni] = __builtin_amdgcn_mfma_f32_16x16x32_bf16(a[mi], b[ni], acc[mi][ni], 0,0,0);
            __builtin_amdgcn_s_setprio(0);
        }
        asm volatile("s_waitcnt vmcnt(0)" ::: "memory");   // this iter's stage: hidden
        __builtin_amdgcn_s_barrier();
        char* tb2 = bc; bc = bn; bn = tb2;
    }
    __builtin_amdgcn_sched_barrier(0);

    // repack C tile into LDS (bank-safe: stride 136) — staging buffers dead
    #pragma unroll
    for (int mi=0;mi<4;mi++)
        #pragma unroll
        for (int ni=0;ni<4;ni++)
            #pragma unroll
            for (int rr=0;rr<4;rr++)
                Cs[(wm+mi*16+lg*4+rr)*136 + wn+ni*16+lr] = f2b(acc[mi][ni][rr]);
    __syncthreads();

    const int rsub = t >> 4;            // 0..15
    const int c8   = (t & 15) * 8;      // constant per thread across store loop

    if (FUSE == 0 || n0 < 1024) {
        const int strd = (FUSE == 0) ? Nout : 1024;
        #pragma unroll
        for (int it = 0; it < 8; it++) {
            int row = it*16 + rsub;
            *(uint4*)(C + (size_t)(m0+row)*strd + n0 + c8) = *(const uint4*)&Cs[row*136 + c8];
        }
    } else if (n0 < 2304) {
        // depthwise causal conv + silu -> xbcc
        const int cbase = n0 - 1024 + c8;
        float4 wreg[8]; float bias[8];
        #pragma unroll
        for (int e=0;e<8;e++) wreg[e] = *(const float4*)(cw + (size_t)(cbase+e)*4);
        {
            float4 b0 = *(const float4*)(cb + cbase);
            float4 b1 = *(const float4*)(cb + cbase + 4);
            bias[0]=b0.x; bias[1]=b0.y; bias[2]=b0.z; bias[3]=b0.w;
            bias[4]=b1.x; bias[5]=b1.y; bias[6]=b1.z; bias[7]=b1.w;
        }
        #pragma unroll
        for (int it = 0; it < 8; it++) {
            int row = it*16 + rsub;
            int sl  = row & (SEQ-1);
            float m3 = (sl >= 3) ? 1.f : 0.f;
            float m2 = (sl >= 2) ? 1.f : 0.f;
            float m1 = (sl >= 1) ? 1.f : 0.f;
            const bf16* sm3 = &Cs[(row-3)*136 + c8];
            const bf16* sm2 = &Cs[(row-2)*136 + c8];
            const bf16* sm1 = &Cs[(row-1)*136 + c8];
            const bf16* sm0 = &Cs[(row  )*136 + c8];
            float a[8];
            #pragma unroll
            for (int e=0;e<8;e++) {
                a[e] = bias[e]
                     + m3 * b2f(sm3[e]) * wreg[e].x
                     + m2 * b2f(sm2[e]) * wreg[e].y
                     + m1 * b2f(sm1[e]) * wreg[e].z
                     +      b2f(sm0[e]) * wreg[e].w;
            }
            bf16 outv[8];
            #pragma unroll
            for (int e=0;e<8;e++) outv[e] = f2b(a[e] / (1.f + __expf(-a[e])));
            *(uint4*)(xbcc + (size_t)(m0+row)*CONV_DIM + cbase) = *(uint4*)&outv[0];
        }
    } else {
        // dt tile: softplus + cumsum scan over each sequence, write dt/cum f32
        for (int p = wid; p < 32; p += 4) {       // (seq-in-tile, head)
            int sq = p >> 4, head = p & 15;
            float raw = b2f(Cs[(sq*64 + lane)*136 + head]) + dt_bias[head];
            float dval = (raw > 20.f) ? raw : log1pf(__expf(raw));
            float Ah = -__expf(A_log[head]);
            float cc = dval * Ah;
            #pragma unroll
            for (int o=1;o<64;o<<=1) { float v = __shfl_up(cc, o); if (lane >= o) cc += v; }
            int tok = m0 + sq*64 + lane;
            dt [(size_t)head*ctok + tok] = dval;
            cum[(size_t)head*ctok + tok] = cc;
        }
    }
}

// ---------------- SSD core v5: token-split + T14 async head prefetch ----------------
// Block = 32 token rows x 16 heads; LDS 79872 B -> 2 blocks/CU. Head hh+1's xs
// global loads issue into REGISTERS before hh's MFMA barrier (T14: latency lands
// under the MFMA phase); the LDS scatter-write uses the prefetched regs.
__global__ __launch_bounds__(256) void k_ssd(const bf16* __restrict__ xbcc,
        const float* __restrict__ dt, const float* __restrict__ cum,
        const float* __restrict__ Dskip, bf16* zio,
        const float* __restrict__ nw, int ctok) {
    extern __shared__ __align__(16) char sm[];
    bf16* yb  = (bf16*)sm;                                   // [32][YPITCH] 66048 B
    bf16* Wb  = (bf16*)(sm + 32*YPITCH*2);                   // [32][72] 4608 B
    bf16* xsT = (bf16*)(sm + 32*YPITCH*2 + 4608);            // [64][72] 9216 B
    const int bid = blockIdx.x;
    const int b   = bid >> 1;
    const int r0  = (bid & 1) * 32;                           // token-row base in batch
    const int t = threadIdx.x;
    const size_t tokbase = (size_t)b*SEQ;
    const int lane = t & 63, lr = lane & 15, lg = lane >> 4;
    const int w = t >> 6;

    // per-thread xs-stage coordinates (constant across heads)
    const int rrA = t >> 3,        cA = (t & 7) * 8;          // chunk 0: rows 0..31
    const int rrB = 32 + (t >> 3), cB = (t & 7) * 8;          // chunk 1: rows 32..63
    const bf16* xsbaseA = xbcc + (tokbase + rrA)*CONV_DIM + cA;
    const bf16* xsbaseB = xbcc + (tokbase + rrB)*CONV_DIM + cB;

    // scores rows [r0 + (w&1)*16, +16) in registers (waves 0/1 only)
    f32x4 sacc[4] = {};
    const int irel0 = (w & 1) * 16;                           // block-relative row base
    if (w < 2) {
        const int i0 = r0 + irel0;
        const bf16* Cbase = xbcc + tokbase*CONV_DIM + D_INNER + D_STATE;
        const bf16* Bbase = xbcc + tokbase*CONV_DIM + D_INNER;
        #pragma unroll
        for (int ks = 0; ks < D_STATE; ks += 32) {
            bf16x8 af = *(const bf16x8*)(Cbase + (size_t)(i0+lr)*CONV_DIM + ks + lg*8);
            #pragma unroll
            for (int jt = 0; jt < 4; jt++) {
                bf16x8 bfr = *(const bf16x8*)(Bbase + (size_t)(jt*16+lr)*CONV_DIM + ks + lg*8);
                sacc[jt] = __builtin_amdgcn_mfma_f32_16x16x32_bf16(af, bfr, sacc[jt], 0,0,0);
            }
        }
    }

    // T14 prologue: prefetch head 0's xs into registers
    uint4 pfA = *(const uint4*)(xsbaseA);
    uint4 pfB = *(const uint4*)(xsbaseB);

    for (int hh = 0; hh < NHEADS; hh++) {
        const size_t cbase = (size_t)hh*ctok + tokbase;
        __syncthreads();   // prev head's MFMA readers done -> Wb/xsT reusable

        // write prefetched xs -> xsT (transpose scatter)
        {
            const bf16* pv = (const bf16*)&pfA;
            #pragma unroll
            for (int e=0;e<8;e++) xsT[(cA+e)*72 + rrA] = pv[e];
            pv = (const bf16*)&pfB;
            #pragma unroll
            for (int e=0;e<8;e++) xsT[(cB+e)*72 + rrB] = pv[e];
        }
        // build Wb rows [irel0, +16) from register scores (waves 0/1)
        if (w < 2) {
            float cum_i[4], cum_j[4], dt_j[4];
            #pragma unroll
            for (int rr=0;rr<4;rr++) cum_i[rr] = cum[cbase + r0 + irel0 + lg*4 + rr];
            #pragma unroll
            for (int jt=0;jt<4;jt++) { int j = jt*16+lr; cum_j[jt]=cum[cbase+j]; dt_j[jt]=dt[cbase+j]; }
            #pragma unroll
            for (int jt=0;jt<4;jt++)
                #pragma unroll
                for (int rr=0;rr<4;rr++) {
                    int irel = irel0 + lg*4 + rr, j = jt*16 + lr;
                    float wv = (j <= r0 + irel)
                             ? sacc[jt][rr] * __expf(cum_i[rr]-cum_j[jt]) * dt_j[jt] : 0.f;
                    Wb[irel*72 + j] = f2b(wv);
                }
        }
        // T14: issue next head's xs loads (land under MFMA + next barrier)
        if (hh + 1 < NHEADS) {
            pfA = *(const uint4*)(xsbaseA + (hh+1)*HEADDIM);
            pfB = *(const uint4*)(xsbaseB + (hh+1)*HEADDIM);
        }
        __syncthreads();

        // y[32x64] = Wb @ xsT^T + Dskip*xs ; wave = rows (w&1)*16, cols (w>>1)*32
        {
            float dsk = Dskip[hh];
            const int ro = (w & 1) * 16, co = (w >> 1) * 32;
            f32x4 yacc[2] = {};
            #pragma unroll
            for (int ks = 0; ks < 64; ks += 32) {
                bf16x8 a = *(const bf16x8*)&Wb[(ro + lr)*72 + ks + lg*8];
                #pragma unroll
                for (int n=0; n<2; n++) {
                    bf16x8 bb = *(const bf16x8*)&xsT[(co + n*16 + lr)*72 + ks + lg*8];
                    yacc[n] = __builtin_amdgcn_mfma_f32_16x16x32_bf16(a, bb, yacc[n], 0,0,0);
                }
            }
            #pragma unroll
            for (int n=0; n<2; n++)
                #pragma unroll
                for (int rr=0; rr<4; rr++) {
                    int row = ro + lg*4 + rr;             // block-relative token
                    int col = co + n*16 + lr;
                    yb[row*YPITCH + hh*HEADDIM + col] =
                        f2b(yacc[n][rr] + dsk * b2f(xsT[col*72 + (r0 + row)]));
                }
        }
    }
    __syncthreads();   // yb complete

    // ---- fused gate + RMS-norm, wave-per-token, in-place into zio ----
    for (int pass = 0; pass < 8; pass++) {
        const int trel = pass*4 + w;                  // 0..31
        const int d0  = lane*16;
        bf16* zrow        = zio + (tokbase + r0 + trel)*D_INNER + d0;
        const bf16* ybrow = yb + trel*YPITCH + d0;
        uint4 yv0 = *(const uint4*)(ybrow);
        uint4 yv1 = *(const uint4*)(ybrow + 8);
        uint4 zv0 = *(const uint4*)(zrow);
        uint4 zv1 = *(const uint4*)(zrow + 8);
        const unsigned* yu0 = (const unsigned*)&yv0;
        const unsigned* yu1 = (const unsigned*)&yv1;
        const unsigned* zu0 = (const unsigned*)&zv0;
        const unsigned* zu1 = (const unsigned*)&zv1;
        float g[16]; float ss = 0.f;
        #pragma unroll
        for (int e=0;e<4;e++) {
            float y0 = bflo(yu0[e]), y1 = bfhi(yu0[e]);
            float z0 = bflo(zu0[e]), z1 = bfhi(zu0[e]);
            float g0 = y0 * z0 / (1.f + __expf(-z0));
            float g1 = y1 * z1 / (1.f + __expf(-z1));
            g[2*e] = g0; g[2*e+1] = g1;
            ss += g0*g0 + g1*g1;
            float y2 = bflo(yu1[e]), y3 = bfhi(yu1[e]);
            float z2 = bflo(zu1[e]), z3 = bfhi(zu1[e]);
            float g2 = y2 * z2 / (1.f + __expf(-z2));
            float g3 = y3 * z3 / (1.f + __expf(-z3));
            g[8+2*e] = g2; g[8+2*e+1] = g3;
            ss += g2*g2 + g3*g3;
        }
        #pragma unroll
        for (int o=32;o>0;o>>=1) ss += __shfl_xor(ss, o);
        float scale = rsqrtf(ss/(float)D_INNER + EPS);
        bf16 outv[16];
        #pragma unroll
        for (int e=0;e<16;e++) outv[e] = f2b(g[e] * scale * nw[d0+e]);
        *(uint4*)zrow     = *(uint4*)&outv[0];
        *(uint4*)(zrow+8) = *(uint4*)&outv[8];
    }
}

// ---------------- hb += layernorm(tmp)*g + b (wave-per-token, no LDS) ----------------
__global__ __launch_bounds__(256) void k_resln(bf16* __restrict__ hb,
        const bf16* __restrict__ tmp,
        const float* __restrict__ g, const float* __restrict__ bb) {
    const int w = threadIdx.x >> 6, lane = threadIdx.x & 63;
    const size_t tok = (size_t)blockIdx.x*4 + w;
    const int d = lane*8;
    const size_t base = tok*D_MODEL + d;
    uint4 u4 = *(const uint4*)(tmp + base);
    const unsigned* uu = (const unsigned*)&u4;
    float v[8];
    #pragma unroll
    for (int e=0;e<4;e++) { v[2*e]=bflo(uu[e]); v[2*e+1]=bfhi(uu[e]); }
    float s=0.f, q=0.f;
    #pragma unroll
    for (int e=0;e<8;e++){ s += v[e]; q += v[e]*v[e]; }
    #pragma unroll
    for (int o=32;o>0;o>>=1){ s += __shfl_xor(s,o); q += __shfl_xor(q,o); }
    float mu  = s/(float)D_MODEL;
    float var = q/(float)D_MODEL - mu*mu;
    float inv = rsqrtf(var + EPS);
    uint4 h4 = *(const uint4*)(hb + base);
    const unsigned* hu = (const unsigned*)&h4;
    float4 g0 = *(const float4*)(g + d);
    float4 g1 = *(const float4*)(g + d + 4);
    float4 b0 = *(const float4*)(bb + d);
    float4 b1 = *(const float4*)(bb + d + 4);
    const float* gp0 = (const float*)&g0; const float* gp1 = (const float*)&g1;
    const float* bp0 = (const float*)&b0; const float* bp1 = (const float*)&b1;
    bf16 o8[8];
    #pragma unroll
    for (int e=0;e<4;e++) {
        float ge0 = (2*e < 4)   ? gp0[2*e]   : gp1[2*e-4];
        float ge1 = (2*e+1 < 4) ? gp0[2*e+1] : gp1[2*e+1-4];
        float be0 = (2*e < 4)   ? bp0[2*e]   : bp1[2*e-4];
        float be1 = (2*e+1 < 4) ? bp0[2*e+1] : bp1[2*e+1-4];
        float h0 = bflo(hu[e]) + (v[2*e]  -mu)*inv*ge0 + be0;
        float h1 = bfhi(hu[e]) + (v[2*e+1]-mu)*inv*ge1 + be1;
        o8[2*e] = f2b(h0); o8[2*e+1] = f2b(h1);
    }
    *(uint4*)(hb + base) = *(uint4*)&o8[0];
}

// ---------------- masked mean-pool over s (bf16 hb) ----------------
__global__ __launch_bounds__(256) void k_pool(const bf16* __restrict__ hb,
        float* __restrict__ pooled) {
    int b = blockIdx.x, t = threadIdx.x;
    __shared__ float ps[64][4];
    __shared__ float pm[64];
    __shared__ float cntS;
    {
        int s = t >> 2, qq = t & 3;
        const bf16* row = hb + ((size_t)b*SEQ + s)*D_MODEL + qq*128;
        float acc = 0;
        #pragma unroll
        for (int e=0;e<16;e++) {
            uint4 v = *(const uint4*)(row + e*8);
            const unsigned* vu = (const unsigned*)&v;
            #pragma unroll
            for (int k=0;k<4;k++) acc += bflo(vu[k]) + bfhi(vu[k]);
        }
        ps[s][qq] = acc;
    }
    __syncthreads();
    if (t < 64) pm[t] = (ps[t][0]+ps[t][1]+ps[t][2]+ps[t][3]) != 0.f ? 1.f : 0.f;
    __syncthreads();
    if (t == 0) { float c=0; for (int s2=0;s2<64;s2++) c+=pm[s2]; cntS = fmaxf(c,1.f); }
    __syncthreads();
    float cnt = cntS;
    #pragma unroll
    for (int rep=0;rep<2;rep++) {
        int d = t + rep*256;
        float acc = 0;
        for (int s2=0;s2<64;s2++)
            acc += b2f(hb[((size_t)b*SEQ+s2)*D_MODEL + d]) * pm[s2];
        pooled[(size_t)b*D_MODEL + d] = acc / cnt;
    }
}

// ---------------- fc1(relu) + fc2 ----------------
__global__ __launch_bounds__(128) void k_fc(const float* __restrict__ pooled,
        const float* __restrict__ w1, const float* __restrict__ b1,
        const float* __restrict__ w2, const float* __restrict__ b2,
        float* __restrict__ out) {
    int b = blockIdx.x, j = threadIdx.x;
    __shared__ float hid[FC_HID];
    const float* p  = pooled + (size_t)b*D_MODEL;
    const float* wr = w1 + (size_t)j*D_MODEL;
    float acc = b1[j];
    for (int d=0; d<D_MODEL; d+=4)
        acc += p[d]*wr[d] + p[d+1]*wr[d+1] + p[d+2]*wr[d+2] + p[d+3]*wr[d+3];
    hid[j] = fmaxf(acc, 0.f);
    __syncthreads();
    if (j < 2) {
        float o = b2[j];
        for (int k=0;k<FC_HID;k++) o += hid[k]*w2[j*FC_HID+k];
        out[b*2 + j] = o;
    }
}

extern "C" void kernel_launch(void* const* d_in, const int* in_sizes, int n_in,
                              void* d_out, int out_size, void* d_ws, size_t ws_size,
                              hipStream_t stream) {
    (void)in_sizes; (void)n_in; (void)out_size;
    const int*   x        = (const int*)  d_in[0];
    const float* emb      = (const float*)d_in[1];
    const float* pos      = (const float*)d_in[2];
    const float* in_proj  = (const float*)d_in[3];
    const float* conv_w   = (const float*)d_in[4];
    const float* conv_b   = (const float*)d_in[5];
    const float* dt_bias  = (const float*)d_in[6];
    const float* A_log    = (const float*)d_in[7];
    const float* D_skip   = (const float*)d_in[8];
    const float* norm_w   = (const float*)d_in[9];
    const float* out_proj = (const float*)d_in[10];
    const float* ln_g     = (const float*)d_in[11];
    const float* ln_b     = (const float*)d_in[12];
    const float* fc1_w    = (const float*)d_in[13];
    const float* fc1_b    = (const float*)d_in[14];
    const float* fc2_w    = (const float*)d_in[15];
    const float* fc2_b    = (const float*)d_in[16];
    float* out = (float*)d_out;

    // allow 79872 B dynamic LDS for token-split SSD (2 blocks/CU)
    const int SSD_LDS = 32*YPITCH*2 + 4608 + 9216;   // 79872
    (void)hipFuncSetAttribute((const void*)k_ssd,
            hipFuncAttributeMaxDynamicSharedMemorySize, SSD_LDS);

    // ---- persistent region: bf16 residual stream + bf16 weights ----
    const size_t HB_B  = (size_t)NTOK * D_MODEL * 2;     // 32 MB bf16 residual
    const size_t WPI_B = (size_t)NPAD * D_MODEL * 2;     // per layer 2.49 MB
    const size_t WPO_B = (size_t)D_MODEL * D_INNER * 2;  // per layer 1 MB
    const size_t PBASE = HB_B + NLAYERS*(WPI_B + WPO_B); // ~39.3 MB

    // transients per token: z 2048 + xbcc 2560 + dt/cum 128 (ybuf eliminated: in-place)
    const size_t PER_TOK = 2048 + 2560 + 128;            // 4736 B
    int CB = BATCH;
    while (CB > 8 && PBASE + (size_t)CB*SEQ*PER_TOK > ws_size) CB >>= 1;
    const int CT = CB * SEQ;
    const int NC = BATCH / CB;

    char* ws = (char*)d_ws;
    bf16*  hb   = (bf16*) (ws);
    bf16*  wpi  = (bf16*) (ws + HB_B);                   // [NLAYERS][NPAD][512]
    bf16*  wpo  = (bf16*) (ws + HB_B + NLAYERS*WPI_B);   // [NLAYERS][512][1024]
    char*  tr   = ws + PBASE;
    bf16*  zbuf = (bf16*) (tr);                          // CT*1024 (z, then gated y in place)
    bf16*  xbcc = (bf16*) (tr + (size_t)CT*2048);        // CT*1280
    float* dt   = (float*)(tr + (size_t)CT*(2048+2560)); // [16][CT]
    float* cum  = dt + (size_t)CT*NHEADS;
    bf16*  tmp  = xbcc;                 // alias: xbcc dead after k_ssd
    float* pooled = (float*)tr;

    // weight conversion (both layers, once per launch)
    for (int l = 0; l < NLAYERS; l++) {
        int t8i = NPAD*D_MODEL/8;
        k_cvtw<<<(t8i+255)/256, 256, 0, stream>>>(in_proj + (size_t)l*D_IN_PROJ*D_MODEL,
                wpi + (size_t)l*NPAD*D_MODEL, D_IN_PROJ, D_MODEL, t8i);
        int t8o = D_MODEL*D_INNER/8;
        k_cvtw<<<(t8o+255)/256, 256, 0, stream>>>(out_proj + (size_t)l*D_MODEL*D_INNER,
                wpo + (size_t)l*D_MODEL*D_INNER, D_MODEL, D_INNER, t8o);
    }

    k_embed<<<(NTOK*128)/256, 256, 0, stream>>>(x, emb, pos, hb);

    const int NBX_I = NPAD/128;     // 19
    const int NBX_O = D_MODEL/128;  // 4

    for (int l = 0; l < NLAYERS; l++) {
        const bf16* wi = wpi + (size_t)l*NPAD*D_MODEL;
        const bf16* wo = wpo + (size_t)l*D_MODEL*D_INNER;
        for (int c = 0; c < NC; c++) {
            const int tok0 = c * CT;
            bf16* hbc = hb + (size_t)tok0 * D_MODEL;
            k_gemm128<1,512><<<(CT/128)*NBX_I, 256, 0, stream>>>(hbc, wi, zbuf,
                    xbcc, dt, cum,
                    conv_w + (size_t)l*CONV_DIM*D_CONV, conv_b + (size_t)l*CONV_DIM,
                    dt_bias + l*NHEADS, A_log + l*NHEADS,
                    NPAD, NBX_I, CT);
            k_ssd<<<CB*2, 256, SSD_LDS, stream>>>(xbcc, dt, cum, D_skip + l*NHEADS,
                    zbuf, norm_w + (size_t)l*D_INNER, CT);
            k_gemm128<0,1024><<<(CT/128)*NBX_O, 256, 0, stream>>>(zbuf, wo, tmp,
                    nullptr, nullptr, nullptr, nullptr, nullptr, nullptr, nullptr,
                    D_MODEL, NBX_O, CT);
            k_resln<<<CT/4, 256, 0, stream>>>(hbc, tmp, ln_g + l*D_MODEL, ln_b + l*D_MODEL);
        }
    }

    k_pool<<<BATCH, 256, 0, stream>>>(hb, pooled);
    k_fc<<<BATCH, FC_HID, 0, stream>>>(pooled, fc1_w, fc1_b, fc2_w, fc2_b, out);
}